// Round 10
// baseline (159.726 us; speedup 1.0000x reference)
//
#include <hip/hip_runtime.h>

typedef unsigned short u16;
typedef u16 u16x4 __attribute__((ext_vector_type(4)));
typedef u16 u16x8 __attribute__((ext_vector_type(8)));
typedef __bf16 bf16x8 __attribute__((ext_vector_type(8)));
typedef float f32x4 __attribute__((ext_vector_type(4)));

#define BB 16
#define TT 512
#define EE 768
#define HH 12
#define DD 64
#define LL 100
#define BT (BB*TT)             /* 8192 */
#define BTE ((size_t)BT*EE)    /* 6291456 */
#define LOG2E 1.44269504f
#define QSCALE (0.125f*LOG2E)  /* 1/sqrt(D)*log2e, folded into Q projection */
#define FIXMAX 44.0f           /* fixed softmax shift (log2 domain) */

__device__ __forceinline__ float bf2f(u16 u){
  union { float f; unsigned int i; } v; v.i = ((unsigned int)u) << 16; return v.f;
}
__device__ __forceinline__ u16 f2bf(float f){
  __bf16 h = (__bf16)f;
  union { __bf16 h; u16 u; } v; v.h = h; return v.u;
}

// async 16B global->LDS DMA. LDS dest = wave-uniform base + lane*16.
__device__ __forceinline__ void gload16(const u16* g, u16* l){
  __builtin_amdgcn_global_load_lds(
      (const __attribute__((address_space(1))) void*)g,
      (__attribute__((address_space(3))) void*)l, 16, 0, 0);
}

// ---------------------------------------------------------------------------
// Merged prep: blocks 0-575 transpose+cast W[4] into bf16 [N][K];
// blocks 576-959 build TEb[128][768] / TEt[768][128]; blocks 960-991 mask bias.
// ---------------------------------------------------------------------------
__global__ __launch_bounds__(256,1) void prep_all_kernel(
    const float* __restrict__ Wq, const float* __restrict__ Wk,
    const float* __restrict__ Wv, const float* __restrict__ Wo,
    u16* __restrict__ WT,
    const float* __restrict__ TE, u16* __restrict__ TEb, u16* __restrict__ TEt,
    const float* __restrict__ mask, float* __restrict__ MBg)
{
  __shared__ float tile[64][65];
  int bx = blockIdx.x;
  int tid = threadIdx.x;
  if (bx < 576){
    int m  = bx / 144, t = bx % 144;
    int tr = t / 12,  tc = t % 12;
    const float* W = (m==0)?Wq : (m==1)?Wk : (m==2)?Wv : Wo;
    u16* dst = WT + (size_t)m * EE * EE;
#pragma unroll
    for (int i=0;i<16;i++){
      int idx = tid + 256*i; int r = idx>>6, c = idx&63;
      tile[r][c] = W[(size_t)(tr*64+r)*EE + tc*64 + c];
    }
    __syncthreads();
#pragma unroll
    for (int i=0;i<16;i++){
      int idx = tid + 256*i; int r = idx>>6, c = idx&63;
      dst[(size_t)(tc*64+r)*EE + tr*64 + c] = f2bf(tile[c][r]);
    }
  } else if (bx < 960){
    int e = (bx - 576)*2 + (tid >> 7);
    int c = tid & 127;
    u16 v = 0;
    if (c < LL) v = f2bf(TE[(size_t)c*EE + e]);
    TEt[(size_t)e*128 + c] = v;
    if (e < 128){
#pragma unroll
      for (int k=c; k<EE; k+=128)
        TEb[(size_t)e*EE + k] = (e < LL) ? f2bf(TE[(size_t)e*EE + k]) : (u16)0;
    }
  } else {
    int i = (bx - 960)*256 + tid;
    MBg[i] = (1.0f - mask[i]) * (-1e9f * LOG2E) - FIXMAX;
  }
}

// ---------------------------------------------------------------------------
// K1: label scores + softmax via MFMA (unchanged).
// ---------------------------------------------------------------------------
__global__ __launch_bounds__(128,4) void label_scores_kernel(
    const float* __restrict__ X, const u16* __restrict__ TEb,
    float* __restrict__ scores_out, u16* __restrict__ att)
{
  __shared__ u16 Xc[32*72];
  __shared__ u16 TEc[112*72];
  int m0 = blockIdx.x * 32;
  int tid = threadIdx.x, lane = tid & 63, w = tid >> 6;
  int l15 = lane & 15, g = lane >> 4;

  f32x4 s[7] = {};
  for (int k0=0; k0<EE; k0+=64){
    __syncthreads();
#pragma unroll
    for (int u=0;u<2;u++){
      int unit = tid + u*128;
      int row = unit >> 3, c8 = (unit & 7) << 3;
      const float* src = &X[(size_t)(m0+row)*EE + k0 + c8];
      float4 a = *(const float4*)src, b = *(const float4*)(src+4);
      u16x8 o;
      o[0]=f2bf(a.x); o[1]=f2bf(a.y); o[2]=f2bf(a.z); o[3]=f2bf(a.w);
      o[4]=f2bf(b.x); o[5]=f2bf(b.y); o[6]=f2bf(b.z); o[7]=f2bf(b.w);
      *(u16x8*)&Xc[row*72 + c8] = o;
    }
#pragma unroll
    for (int u=0;u<7;u++){
      int unit = tid + u*128;
      int l = unit >> 3, c8 = (unit & 7) << 3;
      *(u16x8*)&TEc[l*72 + c8] = *(const u16x8*)&TEb[(size_t)l*EE + k0 + c8];
    }
    __syncthreads();
    bf16x8 af0 = *(const bf16x8*)&Xc[(w*16 + l15)*72 + g*8];
    bf16x8 af1 = *(const bf16x8*)&Xc[(w*16 + l15)*72 + 32 + g*8];
#pragma unroll
    for (int nt=0;nt<7;nt++){
      bf16x8 b0 = *(const bf16x8*)&TEc[(nt*16 + l15)*72 + g*8];
      bf16x8 b1 = *(const bf16x8*)&TEc[(nt*16 + l15)*72 + 32 + g*8];
      s[nt] = __builtin_amdgcn_mfma_f32_16x16x32_bf16(af0, b0, s[nt], 0,0,0);
      s[nt] = __builtin_amdgcn_mfma_f32_16x16x32_bf16(af1, b1, s[nt], 0,0,0);
    }
  }

  int rowb = m0 + w*16 + g*4;
#pragma unroll
  for (int nt=0;nt<7;nt++){
    int col = nt*16 + l15;
    if (col < LL){
#pragma unroll
      for (int r=0;r<4;r++)
        scores_out[(size_t)(rowb + r)*LL + col] = s[nt][r];
    }
  }
  if (l15 >= 4){
#pragma unroll
    for (int r=0;r<4;r++) s[6][r] = -1e30f;
  }
  float inv[4];
#pragma unroll
  for (int r=0;r<4;r++){
    float tm = s[0][r];
#pragma unroll
    for (int nt=1;nt<7;nt++) tm = fmaxf(tm, s[nt][r]);
    tm = fmaxf(tm, __shfl_xor(tm, 1, 16));
    tm = fmaxf(tm, __shfl_xor(tm, 2, 16));
    tm = fmaxf(tm, __shfl_xor(tm, 4, 16));
    tm = fmaxf(tm, __shfl_xor(tm, 8, 16));
    float ps = 0.f;
#pragma unroll
    for (int nt=0;nt<7;nt++){
      float p = exp2f((s[nt][r] - tm) * LOG2E);
      s[nt][r] = p; ps += p;
    }
    ps += __shfl_xor(ps, 1, 16);
    ps += __shfl_xor(ps, 2, 16);
    ps += __shfl_xor(ps, 4, 16);
    ps += __shfl_xor(ps, 8, 16);
    inv[r] = 1.f/ps;
  }
#pragma unroll
  for (int nt=0;nt<7;nt++){
    int col = nt*16 + l15;
#pragma unroll
    for (int r=0;r<4;r++)
      att[(size_t)(rowb + r)*128 + col] = f2bf(s[nt][r] * inv[r]);
  }
  {
    int col = 112 + l15;
#pragma unroll
    for (int r=0;r<4;r++) att[(size_t)(rowb + r)*128 + col] = 0;
  }
}

// ---------------------------------------------------------------------------
// fle GEMM (K=128; epilogue: HT = bf16(X+acc), HU = bf16(X+tp)).
// ---------------------------------------------------------------------------
__global__ __launch_bounds__(256,1) void gemm_fle_kernel(
    const u16* __restrict__ A, const u16* __restrict__ BTw,
    const float* __restrict__ Xf, const float* __restrict__ tp,
    u16* __restrict__ HT, u16* __restrict__ HU, int N, int K)
{
  __shared__ u16 As[128*40];
  __shared__ u16 Bs[128*40];
  int nb = N >> 7;
  int m0 = (blockIdx.x / nb) << 7;
  int n0 = (blockIdx.x % nb) << 7;
  int tid  = threadIdx.x, lane = tid & 63, w = tid >> 6;
  int wm = (w >> 1) << 6, wn = (w & 1) << 6;
  int lr = lane & 15, lk = (lane >> 4) << 3;

  f32x4 acc[4][4] = {};

  for (int k0 = 0; k0 < K; k0 += 32){
    __syncthreads();
#pragma unroll
    for (int i=0;i<2;i++){
      int idx = tid + (i<<8);
      int row = idx >> 2, kq = (idx & 3) << 3;
      *(u16x8*)&As[row*40 + kq] = *(const u16x8*)&A  [(size_t)(m0+row)*K + k0 + kq];
      *(u16x8*)&Bs[row*40 + kq] = *(const u16x8*)&BTw[(size_t)(n0+row)*K + k0 + kq];
    }
    __syncthreads();
    bf16x8 af[4], bfr[4];
#pragma unroll
    for (int i=0;i<4;i++) af [i] = *(const bf16x8*)&As[(wm + i*16 + lr)*40 + lk];
#pragma unroll
    for (int j=0;j<4;j++) bfr[j] = *(const bf16x8*)&Bs[(wn + j*16 + lr)*40 + lk];
#pragma unroll
    for (int i=0;i<4;i++)
#pragma unroll
      for (int j=0;j<4;j++)
        acc[i][j] = __builtin_amdgcn_mfma_f32_16x16x32_bf16(af[i], bfr[j], acc[i][j], 0, 0, 0);
  }

  int rbase = (lane >> 4) << 2;
#pragma unroll
  for (int j=0;j<4;j++){
    int col = n0 + wn + j*16 + lr;
    float tpv = tp[col];
#pragma unroll
    for (int i=0;i<4;i++){
#pragma unroll
      for (int r=0;r<4;r++){
        int row = m0 + wm + i*16 + rbase + r;
        float x = Xf[(size_t)row*EE + col];
        HT[(size_t)row*EE + col] = f2bf(x + acc[i][j][r]);
        HU[(size_t)row*EE + col] = f2bf(x + tpv);
      }
    }
  }
}

// ---------------------------------------------------------------------------
// gemm4 (QKV): 256x256 tile, BK=64, 8 waves (512 thr, 2M x 4N), 2-phase
// DOUBLE-BUFFERED (128KB LDS, 1 block/CU). The vmcnt(0)+barrier now drains
// loads issued one full compute phase (64 MFMA/wave + 24 ds_read) earlier —
// the dbuf STAGE-after-barrier sync structure is the same one field-verified
// in R6/R9; tile/wave geometry is a parameter change. Frag-read swizzle and
// source-pre-swizzle identical to R7 (measured 0 bank conflicts).
// which = nbl/3 selects Q|K|V; Q scaled by QSCALE; V written transposed.
// ---------------------------------------------------------------------------
__global__ __launch_bounds__(512,1) void gemm4_kernel(
    const u16* __restrict__ HU, const u16* __restrict__ HT,
    const u16* __restrict__ Wb,
    const float* __restrict__ bq, const float* __restrict__ bk,
    const float* __restrict__ bv,
    u16* __restrict__ Qb, u16* __restrict__ Kb, u16* __restrict__ Vt)
{
  __shared__ u16 As[2][256*64];   // 64KB
  __shared__ u16 Bs[2][256*64];   // 64KB
  const int K = EE;

  int bid = blockIdx.x;                  // 288 = 32 mb x 9 (3 matrices x 3 nb)
  int cpx = gridDim.x >> 3;              // 36
  int swz = (bid & 7) * cpx + (bid >> 3);
  int mb = swz / 9, nbl = swz % 9;
  int m0 = mb << 8;
  int n0 = (nbl % 3) << 8;
  int which = nbl / 3;

  const u16* Ap; const u16* Wp; const float* bp;
  if (which == 0){ Ap = HU; Wp = Wb;                      bp = bq; }
  else if (which == 1){ Ap = HT; Wp = Wb + (size_t)EE*EE; bp = bk; }
  else { Ap = HT; Wp = Wb + 2*(size_t)EE*EE;              bp = bv; }

  int tid = threadIdx.x, lane = tid & 63, w = tid >> 6;   // w in 0..7
  int wm = (w >> 2) << 7, wn = (w & 3) << 6;              // 2M x 4N
  int lr = lane & 15, g = lane >> 4;
  int lrow = lane >> 3;
  int lchunk = (lane & 7) ^ lrow;        // pre-swizzled source chunk (rule #21)

  f32x4 acc[8][4] = {};

#define GST(buf, k0)                                                             \
  { _Pragma("unroll")                                                            \
    for (int t=0;t<4;t++){                                                       \
      int r0 = w*32 + t*8;                                                       \
      gload16(&Ap[(size_t)(m0 + r0 + lrow)*K + (k0) + (lchunk<<3)], &As[buf][r0*64]); \
      gload16(&Wp[(size_t)(n0 + r0 + lrow)*K + (k0) + (lchunk<<3)], &Bs[buf][r0*64]); } }

  GST(0, 0);

  for (int ks = 0; ks < 12; ks++){
    int k0 = ks << 6, buf = ks & 1;
    __syncthreads();                     // drains DMA issued LAST iteration
    if (ks < 11) GST(buf^1, k0+64);      // next-tile loads fly over compute
#pragma unroll
    for (int kk=0;kk<2;kk++){
      int cs = ((kk<<2) + g) ^ (lr & 7);
      bf16x8 af[8], bfr[4];
#pragma unroll
      for (int i=0;i<8;i++) af [i] = *(const bf16x8*)&As[buf][(wm + i*16 + lr)*64 + (cs<<3)];
#pragma unroll
      for (int j=0;j<4;j++) bfr[j] = *(const bf16x8*)&Bs[buf][(wn + j*16 + lr)*64 + (cs<<3)];
#pragma unroll
      for (int i=0;i<8;i++)
#pragma unroll
        for (int j=0;j<4;j++)
          acc[i][j] = __builtin_amdgcn_mfma_f32_16x16x32_bf16(af[i], bfr[j], acc[i][j], 0, 0, 0);
    }
  }
#undef GST

  int rbase = (lane >> 4) << 2;
#pragma unroll
  for (int j=0;j<4;j++){
    int col = n0 + wn + j*16 + lr;
    float bv_ = bp[col];
    if (which == 2){
      int hh = col >> 6, d = col & 63;
#pragma unroll
      for (int i=0;i<8;i++){
        int row0 = m0 + wm + i*16 + rbase;
        int bb = row0 >> 9, t0 = row0 & 511;
        u16x4 o;
#pragma unroll
        for (int r=0;r<4;r++) o[r] = f2bf(acc[i][j][r] + bv_);
        *(u16x4*)&Vt[((size_t)(bb*HH + hh)*DD + d)*TT + t0] = o;
      }
    } else {
      u16* Cp = (which == 0) ? Qb : Kb;
      float scq = (which == 0) ? QSCALE : 1.0f;
#pragma unroll
      for (int i=0;i<8;i++){
#pragma unroll
        for (int r=0;r<4;r++){
          int row = m0 + wm + i*16 + rbase + r;
          Cp[(size_t)row*EE + col] = f2bf((acc[i][j][r] + bv_) * scq);
        }
      }
    }
  }
}

// ---------------------------------------------------------------------------
// gemm2 (O projection; exact R7 proven version): 128x128, BK=64,
// single-buffer 32KB LDS, global_load_lds + source-pre-swizzle, XCD swizzle.
// ---------------------------------------------------------------------------
template<int NB>
__global__ __launch_bounds__(256,2) void gemm2_kernel(
    const u16* __restrict__ A0, const u16* __restrict__ Wb,
    const float* __restrict__ b0, u16* __restrict__ C0)
{
  __shared__ u16 As[128*64];
  __shared__ u16 Bs[128*64];
  const int K = EE;

  int nwg = gridDim.x;
  int bid = blockIdx.x;
  int cpx = nwg >> 3;
  int swz = (bid & 7) * cpx + (bid >> 3);
  int mb = swz / NB, nb = swz % NB;
  int m0 = mb << 7;
  int n0 = nb << 7;

  int tid = threadIdx.x, lane = tid & 63, w = tid >> 6;
  int wm = (w >> 1) << 6, wn = (w & 1) << 6;
  int lr = lane & 15, g = lane >> 4;
  int lrow = lane >> 3;
  int lchunk = (lane & 7) ^ lrow;

  f32x4 acc[4][4] = {};

  for (int k0 = 0; k0 < K; k0 += 64){
    __syncthreads();
#pragma unroll
    for (int t=0;t<4;t++){
      int r0 = w*32 + t*8;
      gload16(&A0[(size_t)(m0 + r0 + lrow)*K + k0 + (lchunk<<3)], &As[r0*64]);
      gload16(&Wb[(size_t)(n0 + r0 + lrow)*K + k0 + (lchunk<<3)], &Bs[r0*64]);
    }
    __syncthreads();
#pragma unroll
    for (int kk=0;kk<2;kk++){
      int cs = ((kk<<2) + g) ^ (lr & 7);
      bf16x8 af[4], bfr[4];
#pragma unroll
      for (int i=0;i<4;i++) af [i] = *(const bf16x8*)&As[(wm + i*16 + lr)*64 + (cs<<3)];
#pragma unroll
      for (int j=0;j<4;j++) bfr[j] = *(const bf16x8*)&Bs[(wn + j*16 + lr)*64 + (cs<<3)];
#pragma unroll
      for (int i=0;i<4;i++)
#pragma unroll
        for (int j=0;j<4;j++)
          acc[i][j] = __builtin_amdgcn_mfma_f32_16x16x32_bf16(af[i], bfr[j], acc[i][j], 0, 0, 0);
    }
  }

  int rbase = (lane >> 4) << 2;
#pragma unroll
  for (int j=0;j<4;j++){
    int col = n0 + wn + j*16 + lr;
    float bv = b0[col];
#pragma unroll
    for (int i=0;i<4;i++){
#pragma unroll
      for (int r=0;r<4;r++){
        int row = m0 + wm + i*16 + rbase + r;
        C0[(size_t)row*EE + col] = f2bf(acc[i][j][r] + bv);
      }
    }
  }
}

// ---------------------------------------------------------------------------
// K4: MFMA flash attention v3 — FIXED-MAX softmax (unchanged).
// ---------------------------------------------------------------------------
__global__ __launch_bounds__(256,3) void attn_mfma_kernel(
    const u16* __restrict__ Q, const u16* __restrict__ K,
    const u16* __restrict__ VT, const float* __restrict__ MBg,
    u16* __restrict__ CTX)
{
  __shared__ u16 Ks [2][64*64];
  __shared__ u16 VTs[2][64*64];
  __shared__ u16 Pl [4][32*72];

  int bx = blockIdx.x;
  int bh = bx % (BB*HH), q0 = (bx / (BB*HH)) << 7;
  int b = bh / HH, h = bh % HH;
  int tid = threadIdx.x, lane = tid & 63, w = tid >> 6;
  int l15 = lane & 15, g = lane >> 4;
  int wq0 = q0 + w*32;
  size_t rowbase = (size_t)b*TT;
  u16* pw = &Pl[w][0];
  const u16* Kbh = K  + rowbase*EE + h*DD;
  const u16* Vbh = VT + (size_t)bh*DD*TT;
  int lrow = lane >> 3, lchunk = (lane & 7) ^ (lane >> 3);

  bf16x8 qf[2][2];
#pragma unroll
  for (int i=0;i<2;i++)
#pragma unroll
    for (int kk=0;kk<2;kk++)
      qf[i][kk] = *(const bf16x8*)&Q[(rowbase + wq0 + i*16 + l15)*EE + h*DD + kk*32 + g*8];

  f32x4 ctxf[2][4] = {};
  float lrun[2][4] = {};

#define STAGE(buf, k0)                                                          \
  { _Pragma("unroll")                                                           \
    for (int it=0; it<2; ++it){                                                 \
      int r0 = w*16 + it*8;                                                     \
      gload16(&Kbh[(size_t)((k0) + r0 + lrow)*EE + (lchunk<<3)], &Ks [buf][r0*64]); \
      gload16(&Vbh[(size_t)(r0 + lrow)*TT + (k0) + (lchunk<<3)], &VTs[buf][r0*64]); } }

  STAGE(0, 0);

  for (int kt=0; kt<8; ++kt){
    int k0 = kt << 6;
    int buf = kt & 1;
    __syncthreads();
    if (kt < 7) STAGE(buf^1, k0+64);

    float mb[4];
#pragma unroll
    for (int kb=0;kb<4;kb++) mb[kb] = MBg[rowbase + k0 + kb*16 + l15];

    f32x4 s[2][4] = {};
#pragma unroll
    for (int kk=0;kk<2;kk++){
      int cs = ((kk<<2) + g) ^ (l15 & 7);
      bf16x8 kf[4];
#pragma unroll
      for (int kb=0;kb<4;kb++)
        kf[kb] = *(const bf16x8*)&Ks[buf][(kb*16 + l15)*64 + (cs<<3)];
#pragma unroll
      for (int i=0;i<2;i++)
#pragma unroll
        for (int kb=0;kb<4;kb++)
          s[i][kb] = __builtin_amdgcn_mfma_f32_16x16x32_bf16(qf[i][kk], kf[kb], s[i][kb], 0,0,0);
    }

    if ((k0 < wq0 + 32) && (k0 + 64 > wq0)){
#pragma unroll
      for (int i=0;i<2;i++){
        int qr = wq0 + i*16 + g*4;
#pragma unroll
        for (int kb=0;kb<4;kb++){
          int kpos = k0 + kb*16 + l15;
#pragma unroll
          for (int r=0;r<4;r++)
            if (kpos == qr + r) s[i][kb][r] -= 1e9f*LOG2E;
        }
      }
    }

#pragma unroll
    for (int i=0;i<2;i++)
#pragma unroll
      for (int kb=0;kb<4;kb++)
#pragma unroll
        for (int r=0;r<4;r++){
          float p = exp2f(s[i][kb][r] + mb[kb]);
          lrun[i][r] += p;
          pw[(i*16 + g*4 + r)*72 + kb*16 + l15] = f2bf(p);
        }

    bf16x8 pa[2][2];
#pragma unroll
    for (int i=0;i<2;i++)
#pragma unroll
      for (int kk=0;kk<2;kk++)
        pa[i][kk] = *(const bf16x8*)&pw[(i*16 + l15)*72 + kk*32 + g*8];

#pragma unroll
    for (int kk=0;kk<2;kk++){
      int cs = ((kk<<2) + g) ^ (l15 & 7);
      bf16x8 vf[4];
#pragma unroll
      for (int dj=0;dj<4;dj++)
        vf[dj] = *(const bf16x8*)&VTs[buf][(dj*16 + l15)*64 + (cs<<3)];
#pragma unroll
      for (int i=0;i<2;i++)
#pragma unroll
        for (int dj=0;dj<4;dj++)
          ctxf[i][dj] = __builtin_amdgcn_mfma_f32_16x16x32_bf16(pa[i][kk], vf[dj], ctxf[i][dj], 0,0,0);
    }
  }
#undef STAGE

  float inv[2][4];
#pragma unroll
  for (int i=0;i<2;i++)
#pragma unroll
    for (int r=0;r<4;r++){
      float l = lrun[i][r];
      l += __shfl_xor(l, 1, 16);
      l += __shfl_xor(l, 2, 16);
      l += __shfl_xor(l, 4, 16);
      l += __shfl_xor(l, 8, 16);
      inv[i][r] = 1.0f / l;
    }
#pragma unroll
  for (int i=0;i<2;i++)
#pragma unroll
    for (int dj=0;dj<4;dj++)
#pragma unroll
      for (int r=0;r<4;r++)
        pw[(i*16 + g*4 + r)*64 + dj*16 + l15] = f2bf(ctxf[i][dj][r] * inv[i][r]);
#pragma unroll
  for (int t=0;t<4;t++){
    int row = lane >> 1, c = ((lane & 1)<<5) + t*8;
    *(u16x8*)&CTX[(rowbase + wq0 + row)*EE + h*DD + c] = *(const u16x8*)&pw[row*64 + c];
  }
}

// ---------------------------------------------------------------------------
// K5: LayerNorm(attn_out + h_unknown)*g + b + h_truth -> out (f32).
// ---------------------------------------------------------------------------
__global__ __launch_bounds__(192,1) void ln_out_kernel(
    const u16* __restrict__ AO, const u16* __restrict__ HU,
    const u16* __restrict__ HT, const float* __restrict__ g,
    const float* __restrict__ bta, float* __restrict__ out)
{
  __shared__ float red[3];
  int r = blockIdx.x, tid = threadIdx.x;
  size_t base = (size_t)r*EE;
  int e0 = tid*4;
  u16x4 ao = *(const u16x4*)&AO[base+e0];
  u16x4 hu = *(const u16x4*)&HU[base+e0];
  u16x4 ht = *(const u16x4*)&HT[base+e0];
  float x[4];
#pragma unroll
  for (int j=0;j<4;j++) x[j] = bf2f(ao[j]) + bf2f(hu[j]);

  float s = x[0]+x[1]+x[2]+x[3];
#pragma unroll
  for (int o=32;o;o>>=1) s += __shfl_xor(s, o, 64);
  int w = tid>>6;
  if ((tid&63)==0) red[w] = s;
  __syncthreads();
  float mu = (red[0]+red[1]+red[2]) * (1.0f/EE);
  __syncthreads();
  float d2 = 0.f;
#pragma unroll
  for (int j=0;j<4;j++){ float d = x[j]-mu; d2 += d*d; }
#pragma unroll
  for (int o=32;o;o>>=1) d2 += __shfl_xor(d2, o, 64);
  if ((tid&63)==0) red[w] = d2;
  __syncthreads();
  float var = (red[0]+red[1]+red[2]) * (1.0f/EE);
  float rs = rsqrtf(var + 1e-12f);
  float4 gg = *(const float4*)&g[e0];
  float4 bb = *(const float4*)&bta[e0];
  float4 o4;
  o4.x = (x[0]-mu)*rs*gg.x + bb.x + bf2f(ht[0]);
  o4.y = (x[1]-mu)*rs*gg.y + bb.y + bf2f(ht[1]);
  o4.z = (x[2]-mu)*rs*gg.z + bb.z + bf2f(ht[2]);
  o4.w = (x[3]-mu)*rs*gg.w + bb.w + bf2f(ht[3]);
  *(float4*)&out[base+e0] = o4;
}

// ---------------------------------------------------------------------------
extern "C" void kernel_launch(void* const* d_in, const int* in_sizes, int n_in,
                              void* d_out, int out_size, void* d_ws, size_t ws_size,
                              hipStream_t stream)
{
  (void)in_sizes; (void)n_in; (void)out_size; (void)ws_size;
  const float* X    = (const float*)d_in[0];
  const float* mask = (const float*)d_in[1];
  const float* TE   = (const float*)d_in[2];
  const float* tp   = (const float*)d_in[3];
  const float* Wq   = (const float*)d_in[4];
  const float* bq   = (const float*)d_in[5];
  const float* Wk   = (const float*)d_in[6];
  const float* bk   = (const float*)d_in[7];
  const float* Wv   = (const float*)d_in[8];
  const float* bv   = (const float*)d_in[9];
  const float* Wo   = (const float*)d_in[10];
  const float* bo   = (const float*)d_in[11];
  const float* ln_g = (const float*)d_in[12];
  const float* ln_b = (const float*)d_in[13];

  float* out    = (float*)d_out;
  float* scores = out + BTE;

  char* ws = (char*)d_ws;
  const size_t BF = BTE*2;           // bytes of one [BT][E] bf16 buffer
  u16* HT   = (u16*)(ws);
  u16* HU   = (u16*)(ws + BF);
  u16* WT   = (u16*)(ws + 2*BF);     // 4 x [768][768] bf16 (transposed)
  u16* Qb   = (u16*)(ws + 2*BF + (size_t)4*EE*EE*2);
  u16* Kb   = Qb  + BTE;
  u16* VTb  = Kb  + BTE;                       // V transposed: [bh*64+d][512]
  u16* CTXb = VTb + BTE;
  u16* AOb  = CTXb + BTE;
  u16* ATT  = AOb + BTE;                       // [8192][128] bf16
  u16* TEb  = ATT + (size_t)BT*128;            // [128][768] bf16
  u16* TEt  = TEb + (size_t)128*EE;            // [768][128] bf16
  float* MBg = (float*)(TEt + (size_t)EE*128); // [8192] f32 mask bias

  prep_all_kernel<<<dim3(992), dim3(256), 0, stream>>>(
      Wq, Wk, Wv, Wo, WT, TE, TEb, TEt, mask, MBg);

  label_scores_kernel<<<dim3(BT/32), dim3(128), 0, stream>>>(X, TEb, scores, ATT);

  // fle GEMM + fused HT/HU epilogue: M=8192, N=768, K=128
  gemm_fle_kernel<<<dim3((BT/128)*(EE/128)), dim3(256), 0, stream>>>(
      ATT, TEt, X, tp, HT, HU, EE, 128);

  // fused QKV projections, 256^2 double-buffered 2-phase: 32 m x 9 (3 mat x 3 n)
  gemm4_kernel<<<dim3(288), dim3(512), 0, stream>>>(
      HU, HT, WT, bq, bk, bv, Qb, Kb, VTb);

  attn_mfma_kernel<<<dim3(BB*HH*4), dim3(256), 0, stream>>>(Qb, Kb, VTb, MBg, CTXb);

  // O projection: 64 x 6 (exact R7 gemm2)
  gemm2_kernel<6><<<dim3(64*6), dim3(256), 0, stream>>>(
      CTXb, WT + 3*(size_t)EE*EE, bo, AOb);

  ln_out_kernel<<<dim3(BT), dim3(192), 0, stream>>>(AOb, HU, HT, ln_g, ln_b, out);
}

// Round 11
// 139.383 us; speedup vs baseline: 1.1460x; 1.1460x over previous
//
#include <hip/hip_runtime.h>

typedef unsigned short u16;
typedef u16 u16x4 __attribute__((ext_vector_type(4)));
typedef u16 u16x8 __attribute__((ext_vector_type(8)));
typedef __bf16 bf16x8 __attribute__((ext_vector_type(8)));
typedef float f32x4 __attribute__((ext_vector_type(4)));

#define BB 16
#define TT 512
#define EE 768
#define HH 12
#define DD 64
#define LL 100
#define BT (BB*TT)             /* 8192 */
#define BTE ((size_t)BT*EE)    /* 6291456 */
#define LOG2E 1.44269504f
#define QSCALE (0.125f*LOG2E)  /* 1/sqrt(D)*log2e, folded into Q projection */
#define FIXMAX 44.0f           /* fixed softmax shift (log2 domain) */

__device__ __forceinline__ float bf2f(u16 u){
  union { float f; unsigned int i; } v; v.i = ((unsigned int)u) << 16; return v.f;
}
__device__ __forceinline__ u16 f2bf(float f){
  __bf16 h = (__bf16)f;
  union { __bf16 h; u16 u; } v; v.h = h; return v.u;
}

// async 16B global->LDS DMA. LDS dest = wave-uniform base + lane*16.
__device__ __forceinline__ void gload16(const u16* g, u16* l){
  __builtin_amdgcn_global_load_lds(
      (const __attribute__((address_space(1))) void*)g,
      (__attribute__((address_space(3))) void*)l, 16, 0, 0);
}

// ---------------------------------------------------------------------------
// Merged prep: blocks 0-575 transpose+cast W[4] into bf16 [N][K];
// blocks 576-959 build TEb[128][768] / TEt[768][128]; blocks 960-991 mask bias.
// ---------------------------------------------------------------------------
__global__ __launch_bounds__(256,1) void prep_all_kernel(
    const float* __restrict__ Wq, const float* __restrict__ Wk,
    const float* __restrict__ Wv, const float* __restrict__ Wo,
    u16* __restrict__ WT,
    const float* __restrict__ TE, u16* __restrict__ TEb, u16* __restrict__ TEt,
    const float* __restrict__ mask, float* __restrict__ MBg)
{
  __shared__ float tile[64][65];
  int bx = blockIdx.x;
  int tid = threadIdx.x;
  if (bx < 576){
    int m  = bx / 144, t = bx % 144;
    int tr = t / 12,  tc = t % 12;
    const float* W = (m==0)?Wq : (m==1)?Wk : (m==2)?Wv : Wo;
    u16* dst = WT + (size_t)m * EE * EE;
#pragma unroll
    for (int i=0;i<16;i++){
      int idx = tid + 256*i; int r = idx>>6, c = idx&63;
      tile[r][c] = W[(size_t)(tr*64+r)*EE + tc*64 + c];
    }
    __syncthreads();
#pragma unroll
    for (int i=0;i<16;i++){
      int idx = tid + 256*i; int r = idx>>6, c = idx&63;
      dst[(size_t)(tc*64+r)*EE + tr*64 + c] = f2bf(tile[c][r]);
    }
  } else if (bx < 960){
    int e = (bx - 576)*2 + (tid >> 7);
    int c = tid & 127;
    u16 v = 0;
    if (c < LL) v = f2bf(TE[(size_t)c*EE + e]);
    TEt[(size_t)e*128 + c] = v;
    if (e < 128){
#pragma unroll
      for (int k=c; k<EE; k+=128)
        TEb[(size_t)e*EE + k] = (e < LL) ? f2bf(TE[(size_t)e*EE + k]) : (u16)0;
    }
  } else {
    int i = (bx - 960)*256 + tid;
    MBg[i] = (1.0f - mask[i]) * (-1e9f * LOG2E) - FIXMAX;
  }
}

// ---------------------------------------------------------------------------
// K1 v2: label scores + softmax, LDS-FREE. 512 blocks x 1 wave, 16 rows each.
// A-frags built in-register from X (2x float4 -> 8 cvt per kk); B-frags read
// directly from TEb (192KB, L2-resident; same addresses across blocks ->
// broadcast-friendly). No barriers, no staging VALU, full-machine grid
// (old: 256 blocks x 2 waves = half the SIMDs idle).
// ---------------------------------------------------------------------------
__global__ __launch_bounds__(64) void label_scores_kernel(
    const float* __restrict__ X, const u16* __restrict__ TEb,
    float* __restrict__ scores_out, u16* __restrict__ att)
{
  int m0 = blockIdx.x * 16;
  int lane = threadIdx.x;
  int l15 = lane & 15, g = lane >> 4;

  const float* xrow = X + (size_t)(m0 + l15)*EE;
  f32x4 s[7] = {};
  for (int k0=0; k0<EE; k0+=64){
    bf16x8 af[2];
#pragma unroll
    for (int kk=0;kk<2;kk++){
      const float* src = xrow + k0 + kk*32 + g*8;
      float4 a = *(const float4*)src, b = *(const float4*)(src+4);
      bf16x8 o;
      o[0]=(__bf16)a.x; o[1]=(__bf16)a.y; o[2]=(__bf16)a.z; o[3]=(__bf16)a.w;
      o[4]=(__bf16)b.x; o[5]=(__bf16)b.y; o[6]=(__bf16)b.z; o[7]=(__bf16)b.w;
      af[kk] = o;
    }
#pragma unroll
    for (int nt=0;nt<7;nt++){
      bf16x8 b0 = *(const bf16x8*)&TEb[(size_t)(nt*16+l15)*EE + k0 + g*8];
      bf16x8 b1 = *(const bf16x8*)&TEb[(size_t)(nt*16+l15)*EE + k0 + 32 + g*8];
      s[nt] = __builtin_amdgcn_mfma_f32_16x16x32_bf16(af[0], b0, s[nt], 0,0,0);
      s[nt] = __builtin_amdgcn_mfma_f32_16x16x32_bf16(af[1], b1, s[nt], 0,0,0);
    }
  }

  int rowb = m0 + g*4;
#pragma unroll
  for (int nt=0;nt<7;nt++){
    int col = nt*16 + l15;
    if (col < LL){
#pragma unroll
      for (int r=0;r<4;r++)
        scores_out[(size_t)(rowb + r)*LL + col] = s[nt][r];
    }
  }
  if (l15 >= 4){
#pragma unroll
    for (int r=0;r<4;r++) s[6][r] = -1e30f;
  }
  float inv[4];
#pragma unroll
  for (int r=0;r<4;r++){
    float tm = s[0][r];
#pragma unroll
    for (int nt=1;nt<7;nt++) tm = fmaxf(tm, s[nt][r]);
    tm = fmaxf(tm, __shfl_xor(tm, 1, 16));
    tm = fmaxf(tm, __shfl_xor(tm, 2, 16));
    tm = fmaxf(tm, __shfl_xor(tm, 4, 16));
    tm = fmaxf(tm, __shfl_xor(tm, 8, 16));
    float ps = 0.f;
#pragma unroll
    for (int nt=0;nt<7;nt++){
      float p = exp2f((s[nt][r] - tm) * LOG2E);
      s[nt][r] = p; ps += p;
    }
    ps += __shfl_xor(ps, 1, 16);
    ps += __shfl_xor(ps, 2, 16);
    ps += __shfl_xor(ps, 4, 16);
    ps += __shfl_xor(ps, 8, 16);
    inv[r] = 1.f/ps;
  }
#pragma unroll
  for (int nt=0;nt<7;nt++){
    int col = nt*16 + l15;
#pragma unroll
    for (int r=0;r<4;r++)
      att[(size_t)(rowb + r)*128 + col] = f2bf(s[nt][r] * inv[r]);
  }
  {
    int col = 112 + l15;
#pragma unroll
    for (int r=0;r<4;r++) att[(size_t)(rowb + r)*128 + col] = 0;
  }
}

// ---------------------------------------------------------------------------
// fle GEMM (K=128; epilogue: HT = bf16(X+acc), HU = bf16(X+tp)).
// ---------------------------------------------------------------------------
__global__ __launch_bounds__(256,1) void gemm_fle_kernel(
    const u16* __restrict__ A, const u16* __restrict__ BTw,
    const float* __restrict__ Xf, const float* __restrict__ tp,
    u16* __restrict__ HT, u16* __restrict__ HU, int N, int K)
{
  __shared__ u16 As[128*40];
  __shared__ u16 Bs[128*40];
  int nb = N >> 7;
  int m0 = (blockIdx.x / nb) << 7;
  int n0 = (blockIdx.x % nb) << 7;
  int tid  = threadIdx.x, lane = tid & 63, w = tid >> 6;
  int wm = (w >> 1) << 6, wn = (w & 1) << 6;
  int lr = lane & 15, lk = (lane >> 4) << 3;

  f32x4 acc[4][4] = {};

  for (int k0 = 0; k0 < K; k0 += 32){
    __syncthreads();
#pragma unroll
    for (int i=0;i<2;i++){
      int idx = tid + (i<<8);
      int row = idx >> 2, kq = (idx & 3) << 3;
      *(u16x8*)&As[row*40 + kq] = *(const u16x8*)&A  [(size_t)(m0+row)*K + k0 + kq];
      *(u16x8*)&Bs[row*40 + kq] = *(const u16x8*)&BTw[(size_t)(n0+row)*K + k0 + kq];
    }
    __syncthreads();
    bf16x8 af[4], bfr[4];
#pragma unroll
    for (int i=0;i<4;i++) af [i] = *(const bf16x8*)&As[(wm + i*16 + lr)*40 + lk];
#pragma unroll
    for (int j=0;j<4;j++) bfr[j] = *(const bf16x8*)&Bs[(wn + j*16 + lr)*40 + lk];
#pragma unroll
    for (int i=0;i<4;i++)
#pragma unroll
      for (int j=0;j<4;j++)
        acc[i][j] = __builtin_amdgcn_mfma_f32_16x16x32_bf16(af[i], bfr[j], acc[i][j], 0, 0, 0);
  }

  int rbase = (lane >> 4) << 2;
#pragma unroll
  for (int j=0;j<4;j++){
    int col = n0 + wn + j*16 + lr;
    float tpv = tp[col];
#pragma unroll
    for (int i=0;i<4;i++){
#pragma unroll
      for (int r=0;r<4;r++){
        int row = m0 + wm + i*16 + rbase + r;
        float x = Xf[(size_t)row*EE + col];
        HT[(size_t)row*EE + col] = f2bf(x + acc[i][j][r]);
        HU[(size_t)row*EE + col] = f2bf(x + tpv);
      }
    }
  }
}

// ---------------------------------------------------------------------------
// gemm2 (exact R7 proven version): 128x128 tile, BK=64, 4 waves, single-buffer
// 32KB LDS (2 blocks/CU — inter-block overlap hides the barrier drain, m114;
// all dbuf variants regressed: vmcnt(0) in __syncthreads drains the prefetch
// too, so dbuf = single-buffer minus occupancy). global_load_lds w=16 staging,
// source-pre-swizzle (rule #21), XCD-chunked block swizzle.
// FUSED=1: QKV fused, NB=18 (Q scaled by QSCALE; V written transposed).
// ---------------------------------------------------------------------------
template<int NB, int FUSED>
__global__ __launch_bounds__(256,2) void gemm2_kernel(
    const u16* __restrict__ A0, const u16* __restrict__ A1,
    const u16* __restrict__ Wb,
    const float* __restrict__ b0, const float* __restrict__ b1,
    const float* __restrict__ b2,
    u16* __restrict__ C0, u16* __restrict__ C1, u16* __restrict__ C2)
{
  __shared__ u16 As[128*64];
  __shared__ u16 Bs[128*64];
  const int K = EE;

  int nwg = gridDim.x;
  int bid = blockIdx.x;
  int cpx = nwg >> 3;
  int swz = (bid & 7) * cpx + (bid >> 3);
  int mb = swz / NB, nb = swz % NB;
  int m0 = mb << 7;
  int n0 = (FUSED ? (nb % 6) : nb) << 7;

  int which = FUSED ? (nb / 6) : 0;
  const u16* Ap; const u16* Wp; const float* bp; u16* Cp;
  if (!FUSED){ Ap = A0; Wp = Wb; bp = b0; Cp = C0; }
  else {
    if (which == 0){ Ap = A0; Wp = Wb;                      bp = b0; Cp = C0; }
    else if (which == 1){ Ap = A1; Wp = Wb + (size_t)EE*EE; bp = b1; Cp = C1; }
    else { Ap = A1; Wp = Wb + 2*(size_t)EE*EE;              bp = b2; Cp = C2; }
  }

  int tid = threadIdx.x, lane = tid & 63, w = tid >> 6;
  int wm = (w >> 1) << 6, wn = (w & 1) << 6;
  int lr = lane & 15, g = lane >> 4;
  int lrow = lane >> 3;
  int lchunk = (lane & 7) ^ lrow;

  f32x4 acc[4][4] = {};

  for (int k0 = 0; k0 < K; k0 += 64){
    __syncthreads();
#pragma unroll
    for (int t=0;t<4;t++){
      int r0 = w*32 + t*8;
      gload16(&Ap[(size_t)(m0 + r0 + lrow)*K + k0 + (lchunk<<3)], &As[r0*64]);
      gload16(&Wp[(size_t)(n0 + r0 + lrow)*K + k0 + (lchunk<<3)], &Bs[r0*64]);
    }
    __syncthreads();
#pragma unroll
    for (int kk=0;kk<2;kk++){
      int cs = ((kk<<2) + g) ^ (lr & 7);
      bf16x8 af[4], bfr[4];
#pragma unroll
      for (int i=0;i<4;i++) af [i] = *(const bf16x8*)&As[(wm + i*16 + lr)*64 + (cs<<3)];
#pragma unroll
      for (int j=0;j<4;j++) bfr[j] = *(const bf16x8*)&Bs[(wn + j*16 + lr)*64 + (cs<<3)];
#pragma unroll
      for (int i=0;i<4;i++)
#pragma unroll
        for (int j=0;j<4;j++)
          acc[i][j] = __builtin_amdgcn_mfma_f32_16x16x32_bf16(af[i], bfr[j], acc[i][j], 0, 0, 0);
    }
  }

  int rbase = (lane >> 4) << 2;
  float scq = (FUSED && which==0) ? QSCALE : 1.0f;
#pragma unroll
  for (int j=0;j<4;j++){
    int col = n0 + wn + j*16 + lr;
    float bv = bp[col];
    if (FUSED && which == 2){
      int hh = col >> 6, d = col & 63;
#pragma unroll
      for (int i=0;i<4;i++){
        int row0 = m0 + wm + i*16 + rbase;
        int bb = row0 >> 9, t0 = row0 & 511;
        u16x4 o;
#pragma unroll
        for (int r=0;r<4;r++) o[r] = f2bf(acc[i][j][r] + bv);
        *(u16x4*)&Cp[((size_t)(bb*HH + hh)*DD + d)*TT + t0] = o;
      }
    } else {
#pragma unroll
      for (int i=0;i<4;i++){
#pragma unroll
        for (int r=0;r<4;r++){
          int row = m0 + wm + i*16 + rbase + r;
          Cp[(size_t)row*EE + col] = f2bf((acc[i][j][r] + bv) * scq);
        }
      }
    }
  }
}

// ---------------------------------------------------------------------------
// K4: MFMA flash attention v4 — FIXED-MAX softmax. CHANGE vs R7: the MBg
// loads are issued BEFORE STAGE(next), so the compiler's wait for mb is
// vmcnt(4) (stage loads stay in flight) instead of vmcnt(0) (which drained
// the K/V prefetch mid-phase every tile).
// ---------------------------------------------------------------------------
__global__ __launch_bounds__(256,3) void attn_mfma_kernel(
    const u16* __restrict__ Q, const u16* __restrict__ K,
    const u16* __restrict__ VT, const float* __restrict__ MBg,
    u16* __restrict__ CTX)
{
  __shared__ u16 Ks [2][64*64];
  __shared__ u16 VTs[2][64*64];
  __shared__ u16 Pl [4][32*72];

  int bx = blockIdx.x;
  int bh = bx % (BB*HH), q0 = (bx / (BB*HH)) << 7;
  int b = bh / HH, h = bh % HH;
  int tid = threadIdx.x, lane = tid & 63, w = tid >> 6;
  int l15 = lane & 15, g = lane >> 4;
  int wq0 = q0 + w*32;
  size_t rowbase = (size_t)b*TT;
  u16* pw = &Pl[w][0];
  const u16* Kbh = K  + rowbase*EE + h*DD;
  const u16* Vbh = VT + (size_t)bh*DD*TT;
  int lrow = lane >> 3, lchunk = (lane & 7) ^ (lane >> 3);

  bf16x8 qf[2][2];
#pragma unroll
  for (int i=0;i<2;i++)
#pragma unroll
    for (int kk=0;kk<2;kk++)
      qf[i][kk] = *(const bf16x8*)&Q[(rowbase + wq0 + i*16 + l15)*EE + h*DD + kk*32 + g*8];

  f32x4 ctxf[2][4] = {};
  float lrun[2][4] = {};

#define STAGE(buf, k0)                                                          \
  { _Pragma("unroll")                                                           \
    for (int it=0; it<2; ++it){                                                 \
      int r0 = w*16 + it*8;                                                     \
      gload16(&Kbh[(size_t)((k0) + r0 + lrow)*EE + (lchunk<<3)], &Ks [buf][r0*64]); \
      gload16(&Vbh[(size_t)(r0 + lrow)*TT + (k0) + (lchunk<<3)], &VTs[buf][r0*64]); } }

  STAGE(0, 0);

  for (int kt=0; kt<8; ++kt){
    int k0 = kt << 6;
    int buf = kt & 1;
    __syncthreads();                       // drains DMA for buf

    // mb loads FIRST (older than stage loads -> compiler waits vmcnt(4))
    float mb[4];
#pragma unroll
    for (int kb=0;kb<4;kb++) mb[kb] = MBg[rowbase + k0 + kb*16 + l15];

    if (kt < 7) STAGE(buf^1, k0+64);       // prefetch flies over full phase

    // ---- S = Q K^T (log2e domain; Q pre-scaled) ----
    f32x4 s[2][4] = {};
#pragma unroll
    for (int kk=0;kk<2;kk++){
      int cs = ((kk<<2) + g) ^ (l15 & 7);
      bf16x8 kf[4];
#pragma unroll
      for (int kb=0;kb<4;kb++)
        kf[kb] = *(const bf16x8*)&Ks[buf][(kb*16 + l15)*64 + (cs<<3)];
#pragma unroll
      for (int i=0;i<2;i++)
#pragma unroll
        for (int kb=0;kb<4;kb++)
          s[i][kb] = __builtin_amdgcn_mfma_f32_16x16x32_bf16(qf[i][kk], kf[kb], s[i][kb], 0,0,0);
    }

    // ---- diag mask ----
    if ((k0 < wq0 + 32) && (k0 + 64 > wq0)){
#pragma unroll
      for (int i=0;i<2;i++){
        int qr = wq0 + i*16 + g*4;
#pragma unroll
        for (int kb=0;kb<4;kb++){
          int kpos = k0 + kb*16 + l15;
#pragma unroll
          for (int r=0;r<4;r++)
            if (kpos == qr + r) s[i][kb][r] -= 1e9f*LOG2E;
        }
      }
    }

    // ---- p = exp2(s + mb); lane-local sum; P -> LDS (A-frag layout) ----
#pragma unroll
    for (int i=0;i<2;i++)
#pragma unroll
      for (int kb=0;kb<4;kb++)
#pragma unroll
        for (int r=0;r<4;r++){
          float p = exp2f(s[i][kb][r] + mb[kb]);
          lrun[i][r] += p;
          pw[(i*16 + g*4 + r)*72 + kb*16 + l15] = f2bf(p);
        }

    bf16x8 pa[2][2];
#pragma unroll
    for (int i=0;i<2;i++)
#pragma unroll
      for (int kk=0;kk<2;kk++)
        pa[i][kk] = *(const bf16x8*)&pw[(i*16 + l15)*72 + kk*32 + g*8];

    // ---- ctx += P V ----
#pragma unroll
    for (int kk=0;kk<2;kk++){
      int cs = ((kk<<2) + g) ^ (l15 & 7);
      bf16x8 vf[4];
#pragma unroll
      for (int dj=0;dj<4;dj++)
        vf[dj] = *(const bf16x8*)&VTs[buf][(dj*16 + l15)*64 + (cs<<3)];
#pragma unroll
      for (int i=0;i<2;i++)
#pragma unroll
        for (int dj=0;dj<4;dj++)
          ctxf[i][dj] = __builtin_amdgcn_mfma_f32_16x16x32_bf16(pa[i][kk], vf[dj], ctxf[i][dj], 0,0,0);
    }
  }
#undef STAGE

  float inv[2][4];
#pragma unroll
  for (int i=0;i<2;i++)
#pragma unroll
    for (int r=0;r<4;r++){
      float l = lrun[i][r];
      l += __shfl_xor(l, 1, 16);
      l += __shfl_xor(l, 2, 16);
      l += __shfl_xor(l, 4, 16);
      l += __shfl_xor(l, 8, 16);
      inv[i][r] = 1.0f / l;
    }
#pragma unroll
  for (int i=0;i<2;i++)
#pragma unroll
    for (int dj=0;dj<4;dj++)
#pragma unroll
      for (int r=0;r<4;r++)
        pw[(i*16 + g*4 + r)*64 + dj*16 + l15] = f2bf(ctxf[i][dj][r] * inv[i][r]);
#pragma unroll
  for (int t=0;t<4;t++){
    int row = lane >> 1, c = ((lane & 1)<<5) + t*8;
    *(u16x8*)&CTX[(rowbase + wq0 + row)*EE + h*DD + c] = *(const u16x8*)&pw[row*64 + c];
  }
}

// ---------------------------------------------------------------------------
// K5: LayerNorm(attn_out + h_unknown)*g + b + h_truth -> out (f32).
// ---------------------------------------------------------------------------
__global__ __launch_bounds__(192,1) void ln_out_kernel(
    const u16* __restrict__ AO, const u16* __restrict__ HU,
    const u16* __restrict__ HT, const float* __restrict__ g,
    const float* __restrict__ bta, float* __restrict__ out)
{
  __shared__ float red[3];
  int r = blockIdx.x, tid = threadIdx.x;
  size_t base = (size_t)r*EE;
  int e0 = tid*4;
  u16x4 ao = *(const u16x4*)&AO[base+e0];
  u16x4 hu = *(const u16x4*)&HU[base+e0];
  u16x4 ht = *(const u16x4*)&HT[base+e0];
  float x[4];
#pragma unroll
  for (int j=0;j<4;j++) x[j] = bf2f(ao[j]) + bf2f(hu[j]);

  float s = x[0]+x[1]+x[2]+x[3];
#pragma unroll
  for (int o=32;o;o>>=1) s += __shfl_xor(s, o, 64);
  int w = tid>>6;
  if ((tid&63)==0) red[w] = s;
  __syncthreads();
  float mu = (red[0]+red[1]+red[2]) * (1.0f/EE);
  __syncthreads();
  float d2 = 0.f;
#pragma unroll
  for (int j=0;j<4;j++){ float d = x[j]-mu; d2 += d*d; }
#pragma unroll
  for (int o=32;o;o>>=1) d2 += __shfl_xor(d2, o, 64);
  if ((tid&63)==0) red[w] = d2;
  __syncthreads();
  float var = (red[0]+red[1]+red[2]) * (1.0f/EE);
  float rs = rsqrtf(var + 1e-12f);
  float4 gg = *(const float4*)&g[e0];
  float4 bb = *(const float4*)&bta[e0];
  float4 o4;
  o4.x = (x[0]-mu)*rs*gg.x + bb.x + bf2f(ht[0]);
  o4.y = (x[1]-mu)*rs*gg.y + bb.y + bf2f(ht[1]);
  o4.z = (x[2]-mu)*rs*gg.z + bb.z + bf2f(ht[2]);
  o4.w = (x[3]-mu)*rs*gg.w + bb.w + bf2f(ht[3]);
  *(float4*)&out[base+e0] = o4;
}

// ---------------------------------------------------------------------------
extern "C" void kernel_launch(void* const* d_in, const int* in_sizes, int n_in,
                              void* d_out, int out_size, void* d_ws, size_t ws_size,
                              hipStream_t stream)
{
  (void)in_sizes; (void)n_in; (void)out_size; (void)ws_size;
  const float* X    = (const float*)d_in[0];
  const float* mask = (const float*)d_in[1];
  const float* TE   = (const float*)d_in[2];
  const float* tp   = (const float*)d_in[3];
  const float* Wq   = (const float*)d_in[4];
  const float* bq   = (const float*)d_in[5];
  const float* Wk   = (const float*)d_in[6];
  const float* bk   = (const float*)d_in[7];
  const float* Wv   = (const float*)d_in[8];
  const float* bv   = (const float*)d_in[9];
  const float* Wo   = (const float*)d_in[10];
  const float* bo   = (const float*)d_in[11];
  const float* ln_g = (const float*)d_in[12];
  const float* ln_b = (const float*)d_in[13];

  float* out    = (float*)d_out;
  float* scores = out + BTE;

  char* ws = (char*)d_ws;
  const size_t BF = BTE*2;           // bytes of one [BT][E] bf16 buffer
  u16* HT   = (u16*)(ws);
  u16* HU   = (u16*)(ws + BF);
  u16* WT   = (u16*)(ws + 2*BF);     // 4 x [768][768] bf16 (transposed)
  u16* Qb   = (u16*)(ws + 2*BF + (size_t)4*EE*EE*2);
  u16* Kb   = Qb  + BTE;
  u16* VTb  = Kb  + BTE;                       // V transposed: [bh*64+d][512]
  u16* CTXb = VTb + BTE;
  u16* AOb  = CTXb + BTE;
  u16* ATT  = AOb + BTE;                       // [8192][128] bf16
  u16* TEb  = ATT + (size_t)BT*128;            // [128][768] bf16
  u16* TEt  = TEb + (size_t)128*EE;            // [768][128] bf16
  float* MBg = (float*)(TEt + (size_t)EE*128); // [8192] f32 mask bias

  prep_all_kernel<<<dim3(992), dim3(256), 0, stream>>>(
      Wq, Wk, Wv, Wo, WT, TE, TEb, TEt, mask, MBg);

  label_scores_kernel<<<dim3(BT/16), dim3(64), 0, stream>>>(X, TEb, scores, ATT);

  // fle GEMM + fused HT/HU epilogue: M=8192, N=768, K=128
  gemm_fle_kernel<<<dim3((BT/128)*(EE/128)), dim3(256), 0, stream>>>(
      ATT, TEt, X, tp, HT, HU, EE, 128);

  // fused QKV projections (Q scaled, V written transposed): 64 m x 18 n
  gemm2_kernel<18,1><<<dim3(64*18), dim3(256), 0, stream>>>(
      HU, HT, WT, bq, bk, bv, Qb, Kb, VTb);

  attn_mfma_kernel<<<dim3(BB*HH*4), dim3(256), 0, stream>>>(Qb, Kb, VTb, MBg, CTXb);

  // O projection: 64 x 6
  gemm2_kernel<6,0><<<dim3(64*6), dim3(256), 0, stream>>>(
      CTXb, nullptr, WT + 3*(size_t)EE*EE, bo, nullptr, nullptr, AOb, nullptr, nullptr);

  ln_out_kernel<<<dim3(BT), dim3(192), 0, stream>>>(AOb, HU, HT, ln_g, ln_b, out);
}

// Round 12
// 119.946 us; speedup vs baseline: 1.3316x; 1.1620x over previous
//
#include <hip/hip_runtime.h>

typedef unsigned char u8;
typedef unsigned short u16;
typedef u16 u16x4 __attribute__((ext_vector_type(4)));
typedef u16 u16x8 __attribute__((ext_vector_type(8)));
typedef __bf16 bf16x8 __attribute__((ext_vector_type(8)));
typedef float f32x2 __attribute__((ext_vector_type(2)));
typedef float f32x4 __attribute__((ext_vector_type(4)));

#define BB 16
#define TT 512
#define EE 768
#define HH 12
#define DD 64
#define LL 100
#define BT (BB*TT)             /* 8192 */
#define BTE ((size_t)BT*EE)    /* 6291456 */
#define LOG2E 1.44269504f
#define QSCALE (0.125f*LOG2E)  /* 1/sqrt(D)*log2e, folded into Q projection */
#define FIXMAX 44.0f           /* fixed softmax shift (log2 domain) */

__device__ __forceinline__ float bf2f(u16 u){
  union { float f; unsigned int i; } v; v.i = ((unsigned int)u) << 16; return v.f;
}
__device__ __forceinline__ u16 f2bf(float f){
  __bf16 h = (__bf16)f;
  union { __bf16 h; u16 u; } v; v.h = h; return v.u;
}
// fp8 e4m3 (OCP on gfx950) pack/unpack via HW cvt
__device__ __forceinline__ u16 pk_fp8(float a, float b){
  return (u16)(__builtin_amdgcn_cvt_pk_fp8_f32(a, b, 0, false) & 0xffff);
}
__device__ __forceinline__ u8 f2fp8(float a){
  return (u8)(__builtin_amdgcn_cvt_pk_fp8_f32(a, 0.f, 0, false) & 0xff);
}

// async 16B global->LDS DMA. LDS dest = wave-uniform base + lane*16.
__device__ __forceinline__ void gload16(const void* g, void* l){
  __builtin_amdgcn_global_load_lds(
      (const __attribute__((address_space(1))) void*)g,
      (__attribute__((address_space(3))) void*)l, 16, 0, 0);
}

// ---------------------------------------------------------------------------
// Merged prep: blocks 0-575 transpose+cast W[4] into FP8 [N][K];
// blocks 576-959 build TEb[128][768] / TEt[768][128] bf16; 960-991 mask bias.
// ---------------------------------------------------------------------------
__global__ __launch_bounds__(256,1) void prep_all_kernel(
    const float* __restrict__ Wq, const float* __restrict__ Wk,
    const float* __restrict__ Wv, const float* __restrict__ Wo,
    u8* __restrict__ WT8,
    const float* __restrict__ TE, u16* __restrict__ TEb, u16* __restrict__ TEt,
    const float* __restrict__ mask, float* __restrict__ MBg)
{
  __shared__ float tile[64][65];
  int bx = blockIdx.x;
  int tid = threadIdx.x;
  if (bx < 576){
    int m  = bx / 144, t = bx % 144;
    int tr = t / 12,  tc = t % 12;
    const float* W = (m==0)?Wq : (m==1)?Wk : (m==2)?Wv : Wo;
    u8* dst = WT8 + (size_t)m * EE * EE;
#pragma unroll
    for (int i=0;i<16;i++){
      int idx = tid + 256*i; int r = idx>>6, c = idx&63;
      tile[r][c] = W[(size_t)(tr*64+r)*EE + tc*64 + c];
    }
    __syncthreads();
    // dst[n][k] = W[k][n] in fp8, packed pairs along k
#pragma unroll
    for (int i=0;i<8;i++){
      int idx = tid + 256*i;          // 2048 = 64 r x 32 col-pairs
      int r = idx >> 5, cp = idx & 31;
      u16 pk = pk_fp8(tile[cp*2][r], tile[cp*2+1][r]);
      *(u16*)&dst[(size_t)(tc*64+r)*EE + tr*64 + cp*2] = pk;
    }
  } else if (bx < 960){
    int e = (bx - 576)*2 + (tid >> 7);
    int c = tid & 127;
    u16 v = 0;
    if (c < LL) v = f2bf(TE[(size_t)c*EE + e]);
    TEt[(size_t)e*128 + c] = v;
    if (e < 128){
#pragma unroll
      for (int k=c; k<EE; k+=128)
        TEb[(size_t)e*EE + k] = (e < LL) ? f2bf(TE[(size_t)e*EE + k]) : (u16)0;
    }
  } else {
    int i = (bx - 960)*256 + tid;
    MBg[i] = (1.0f - mask[i]) * (-1e9f * LOG2E) - FIXMAX;
  }
}

// ---------------------------------------------------------------------------
// K1 v2: label scores + softmax, LDS-free (unchanged from R11).
// ---------------------------------------------------------------------------
__global__ __launch_bounds__(64) void label_scores_kernel(
    const float* __restrict__ X, const u16* __restrict__ TEb,
    float* __restrict__ scores_out, u16* __restrict__ att)
{
  int m0 = blockIdx.x * 16;
  int lane = threadIdx.x;
  int l15 = lane & 15, g = lane >> 4;

  const float* xrow = X + (size_t)(m0 + l15)*EE;
  f32x4 s[7] = {};
  for (int k0=0; k0<EE; k0+=64){
    bf16x8 af[2];
#pragma unroll
    for (int kk=0;kk<2;kk++){
      const float* src = xrow + k0 + kk*32 + g*8;
      float4 a = *(const float4*)src, b = *(const float4*)(src+4);
      bf16x8 o;
      o[0]=(__bf16)a.x; o[1]=(__bf16)a.y; o[2]=(__bf16)a.z; o[3]=(__bf16)a.w;
      o[4]=(__bf16)b.x; o[5]=(__bf16)b.y; o[6]=(__bf16)b.z; o[7]=(__bf16)b.w;
      af[kk] = o;
    }
#pragma unroll
    for (int nt=0;nt<7;nt++){
      bf16x8 b0 = *(const bf16x8*)&TEb[(size_t)(nt*16+l15)*EE + k0 + g*8];
      bf16x8 b1 = *(const bf16x8*)&TEb[(size_t)(nt*16+l15)*EE + k0 + 32 + g*8];
      s[nt] = __builtin_amdgcn_mfma_f32_16x16x32_bf16(af[0], b0, s[nt], 0,0,0);
      s[nt] = __builtin_amdgcn_mfma_f32_16x16x32_bf16(af[1], b1, s[nt], 0,0,0);
    }
  }

  int rowb = m0 + g*4;
#pragma unroll
  for (int nt=0;nt<7;nt++){
    int col = nt*16 + l15;
    if (col < LL){
#pragma unroll
      for (int r=0;r<4;r++)
        scores_out[(size_t)(rowb + r)*LL + col] = s[nt][r];
    }
  }
  if (l15 >= 4){
#pragma unroll
    for (int r=0;r<4;r++) s[6][r] = -1e30f;
  }
  float inv[4];
#pragma unroll
  for (int r=0;r<4;r++){
    float tm = s[0][r];
#pragma unroll
    for (int nt=1;nt<7;nt++) tm = fmaxf(tm, s[nt][r]);
    tm = fmaxf(tm, __shfl_xor(tm, 1, 16));
    tm = fmaxf(tm, __shfl_xor(tm, 2, 16));
    tm = fmaxf(tm, __shfl_xor(tm, 4, 16));
    tm = fmaxf(tm, __shfl_xor(tm, 8, 16));
    float ps = 0.f;
#pragma unroll
    for (int nt=0;nt<7;nt++){
      float p = exp2f((s[nt][r] - tm) * LOG2E);
      s[nt][r] = p; ps += p;
    }
    ps += __shfl_xor(ps, 1, 16);
    ps += __shfl_xor(ps, 2, 16);
    ps += __shfl_xor(ps, 4, 16);
    ps += __shfl_xor(ps, 8, 16);
    inv[r] = 1.f/ps;
  }
#pragma unroll
  for (int nt=0;nt<7;nt++){
    int col = nt*16 + l15;
#pragma unroll
    for (int r=0;r<4;r++)
      att[(size_t)(rowb + r)*128 + col] = f2bf(s[nt][r] * inv[r]);
  }
  {
    int col = 112 + l15;
#pragma unroll
    for (int r=0;r<4;r++) att[(size_t)(rowb + r)*128 + col] = 0;
  }
}

// ---------------------------------------------------------------------------
// fle GEMM (bf16 interior, K=128): HT8 = fp8(X+acc), HU8 = fp8(X+tp).
// ---------------------------------------------------------------------------
__global__ __launch_bounds__(256,1) void gemm_fle_kernel(
    const u16* __restrict__ A, const u16* __restrict__ BTw,
    const float* __restrict__ Xf, const float* __restrict__ tp,
    u8* __restrict__ HT8, u8* __restrict__ HU8, int N, int K)
{
  __shared__ u16 As[128*40];
  __shared__ u16 Bs[128*40];
  int nb = N >> 7;
  int m0 = (blockIdx.x / nb) << 7;
  int n0 = (blockIdx.x % nb) << 7;
  int tid  = threadIdx.x, lane = tid & 63, w = tid >> 6;
  int wm = (w >> 1) << 6, wn = (w & 1) << 6;
  int lr = lane & 15, lk = (lane >> 4) << 3;

  f32x4 acc[4][4] = {};

  for (int k0 = 0; k0 < K; k0 += 32){
    __syncthreads();
#pragma unroll
    for (int i=0;i<2;i++){
      int idx = tid + (i<<8);
      int row = idx >> 2, kq = (idx & 3) << 3;
      *(u16x8*)&As[row*40 + kq] = *(const u16x8*)&A  [(size_t)(m0+row)*K + k0 + kq];
      *(u16x8*)&Bs[row*40 + kq] = *(const u16x8*)&BTw[(size_t)(n0+row)*K + k0 + kq];
    }
    __syncthreads();
    bf16x8 af[4], bfr[4];
#pragma unroll
    for (int i=0;i<4;i++) af [i] = *(const bf16x8*)&As[(wm + i*16 + lr)*40 + lk];
#pragma unroll
    for (int j=0;j<4;j++) bfr[j] = *(const bf16x8*)&Bs[(wn + j*16 + lr)*40 + lk];
#pragma unroll
    for (int i=0;i<4;i++)
#pragma unroll
      for (int j=0;j<4;j++)
        acc[i][j] = __builtin_amdgcn_mfma_f32_16x16x32_bf16(af[i], bfr[j], acc[i][j], 0, 0, 0);
  }

  int rbase = (lane >> 4) << 2;
#pragma unroll
  for (int j=0;j<4;j++){
    int col = n0 + wn + j*16 + lr;
    float tpv = tp[col];
#pragma unroll
    for (int i=0;i<4;i++){
#pragma unroll
      for (int r=0;r<4;r++){
        int row = m0 + wm + i*16 + rbase + r;
        float x = Xf[(size_t)row*EE + col];
        HT8[(size_t)row*EE + col] = f2fp8(x + acc[i][j][r]);
        HU8[(size_t)row*EE + col] = f2fp8(x + tpv);
      }
    }
  }
}

// ---------------------------------------------------------------------------
// gemm8: FP8 projection GEMM. Same proven 2-barrier structure as R7's gemm2 —
// BYTE-IDENTICAL staging geometry (row = 128 B = 128 fp8 vs 64 bf16), BK=128
// elements -> 6 k-steps (half the barriers, half the gload16s of bf16).
// Frag reads: b64 at chunk cs = (2kk + (g>>1)) ^ (lr&7), half (g&1)*8
// (bank-checked: 2-way = free). MFMA: 16x16x32_fp8_fp8 (A/B = i64, 8 fp8/lane
// contiguous k — same lane->k mapping as bf16). Outputs remain bf16.
// FUSED=1: QKV, NB=18 (Q scaled by QSCALE; V written transposed per head).
// ---------------------------------------------------------------------------
template<int NB, int FUSED>
__global__ __launch_bounds__(256,2) void gemm8_kernel(
    const u8* __restrict__ A0, const u8* __restrict__ A1,
    const u8* __restrict__ Wb,
    const float* __restrict__ b0, const float* __restrict__ b1,
    const float* __restrict__ b2,
    u16* __restrict__ C0, u16* __restrict__ C1, u16* __restrict__ C2)
{
  __shared__ __align__(16) u8 As[128*128];
  __shared__ __align__(16) u8 Bs[128*128];
  const int K = EE;   // bytes per row (1B/elt)

  int nwg = gridDim.x;
  int bid = blockIdx.x;
  int cpx = nwg >> 3;
  int swz = (bid & 7) * cpx + (bid >> 3);
  int mb = swz / NB, nb = swz % NB;
  int m0 = mb << 7;
  int n0 = (FUSED ? (nb % 6) : nb) << 7;

  int which = FUSED ? (nb / 6) : 0;
  const u8* Ap; const u8* Wp; const float* bp; u16* Cp;
  if (!FUSED){ Ap = A0; Wp = Wb; bp = b0; Cp = C0; }
  else {
    if (which == 0){ Ap = A0; Wp = Wb;                      bp = b0; Cp = C0; }
    else if (which == 1){ Ap = A1; Wp = Wb + (size_t)EE*EE; bp = b1; Cp = C1; }
    else { Ap = A1; Wp = Wb + 2*(size_t)EE*EE;              bp = b2; Cp = C2; }
  }

  int tid = threadIdx.x, lane = tid & 63, w = tid >> 6;
  int wm = (w >> 1) << 6, wn = (w & 1) << 6;
  int lr = lane & 15, g = lane >> 4;
  int lrow = lane >> 3;
  int lchunk = (lane & 7) ^ lrow;          // source pre-swizzle (rule #21)

  f32x4 acc[4][4] = {};

  for (int k0 = 0; k0 < K; k0 += 128){
    __syncthreads();
#pragma unroll
    for (int t=0;t<4;t++){
      int r0 = w*32 + t*8;
      gload16(&Ap[(size_t)(m0 + r0 + lrow)*K + k0 + (lchunk<<4)], &As[r0*128]);
      gload16(&Wp[(size_t)(n0 + r0 + lrow)*K + k0 + (lchunk<<4)], &Bs[r0*128]);
    }
    __syncthreads();
#pragma unroll
    for (int kk=0;kk<4;kk++){
      int cs  = ((kk<<1) + (g>>1)) ^ (lr & 7);
      int off = (cs<<4) + ((g&1)<<3);
      long af[4], bfr[4];
#pragma unroll
      for (int i=0;i<4;i++) af [i] = *(const long*)&As[(wm + i*16 + lr)*128 + off];
#pragma unroll
      for (int j=0;j<4;j++) bfr[j] = *(const long*)&Bs[(wn + j*16 + lr)*128 + off];
#pragma unroll
      for (int i=0;i<4;i++)
#pragma unroll
        for (int j=0;j<4;j++)
          acc[i][j] = __builtin_amdgcn_mfma_f32_16x16x32_fp8_fp8(af[i], bfr[j], acc[i][j], 0, 0, 0);
    }
  }

  int rbase = (lane >> 4) << 2;
  float scq = (FUSED && which==0) ? QSCALE : 1.0f;
#pragma unroll
  for (int j=0;j<4;j++){
    int col = n0 + wn + j*16 + lr;
    float bv = bp[col];
    if (FUSED && which == 2){
      int hh = col >> 6, d = col & 63;
#pragma unroll
      for (int i=0;i<4;i++){
        int row0 = m0 + wm + i*16 + rbase;
        int bb = row0 >> 9, t0 = row0 & 511;
        u16x4 o;
#pragma unroll
        for (int r=0;r<4;r++) o[r] = f2bf(acc[i][j][r] + bv);
        *(u16x4*)&Cp[((size_t)(bb*HH + hh)*DD + d)*TT + t0] = o;
      }
    } else {
#pragma unroll
      for (int i=0;i<4;i++){
#pragma unroll
        for (int r=0;r<4;r++){
          int row = m0 + wm + i*16 + rbase + r;
          Cp[(size_t)row*EE + col] = f2bf((acc[i][j][r] + bv) * scq);
        }
      }
    }
  }
}

// ---------------------------------------------------------------------------
// K4: MFMA flash attention v4 — fixed-max softmax, bf16 throughout (R11).
// Only change: CTX written as fp8 for the O projection.
// ---------------------------------------------------------------------------
__global__ __launch_bounds__(256,3) void attn_mfma_kernel(
    const u16* __restrict__ Q, const u16* __restrict__ K,
    const u16* __restrict__ VT, const float* __restrict__ MBg,
    u8* __restrict__ CTX8)
{
  __shared__ u16 Ks [2][64*64];
  __shared__ u16 VTs[2][64*64];
  __shared__ u16 Pl [4][32*72];

  int bx = blockIdx.x;
  int bh = bx % (BB*HH), q0 = (bx / (BB*HH)) << 7;
  int b = bh / HH, h = bh % HH;
  int tid = threadIdx.x, lane = tid & 63, w = tid >> 6;
  int l15 = lane & 15, g = lane >> 4;
  int wq0 = q0 + w*32;
  size_t rowbase = (size_t)b*TT;
  u16* pw = &Pl[w][0];
  const u16* Kbh = K  + rowbase*EE + h*DD;
  const u16* Vbh = VT + (size_t)bh*DD*TT;
  int lrow = lane >> 3, lchunk = (lane & 7) ^ (lane >> 3);

  bf16x8 qf[2][2];
#pragma unroll
  for (int i=0;i<2;i++)
#pragma unroll
    for (int kk=0;kk<2;kk++)
      qf[i][kk] = *(const bf16x8*)&Q[(rowbase + wq0 + i*16 + l15)*EE + h*DD + kk*32 + g*8];

  f32x4 ctxf[2][4] = {};
  float lrun[2][4] = {};

#define STAGE(buf, k0)                                                          \
  { _Pragma("unroll")                                                           \
    for (int it=0; it<2; ++it){                                                 \
      int r0 = w*16 + it*8;                                                     \
      gload16(&Kbh[(size_t)((k0) + r0 + lrow)*EE + (lchunk<<3)], &Ks [buf][r0*64]); \
      gload16(&Vbh[(size_t)(r0 + lrow)*TT + (k0) + (lchunk<<3)], &VTs[buf][r0*64]); } }

  STAGE(0, 0);

  for (int kt=0; kt<8; ++kt){
    int k0 = kt << 6;
    int buf = kt & 1;
    __syncthreads();

    // mb loads FIRST (older than stage loads -> compiler waits vmcnt(4))
    float mb[4];
#pragma unroll
    for (int kb=0;kb<4;kb++) mb[kb] = MBg[rowbase + k0 + kb*16 + l15];

    if (kt < 7) STAGE(buf^1, k0+64);

    f32x4 s[2][4] = {};
#pragma unroll
    for (int kk=0;kk<2;kk++){
      int cs = ((kk<<2) + g) ^ (l15 & 7);
      bf16x8 kf[4];
#pragma unroll
      for (int kb=0;kb<4;kb++)
        kf[kb] = *(const bf16x8*)&Ks[buf][(kb*16 + l15)*64 + (cs<<3)];
#pragma unroll
      for (int i=0;i<2;i++)
#pragma unroll
        for (int kb=0;kb<4;kb++)
          s[i][kb] = __builtin_amdgcn_mfma_f32_16x16x32_bf16(qf[i][kk], kf[kb], s[i][kb], 0,0,0);
    }

    if ((k0 < wq0 + 32) && (k0 + 64 > wq0)){
#pragma unroll
      for (int i=0;i<2;i++){
        int qr = wq0 + i*16 + g*4;
#pragma unroll
        for (int kb=0;kb<4;kb++){
          int kpos = k0 + kb*16 + l15;
#pragma unroll
          for (int r=0;r<4;r++)
            if (kpos == qr + r) s[i][kb][r] -= 1e9f*LOG2E;
        }
      }
    }

#pragma unroll
    for (int i=0;i<2;i++)
#pragma unroll
      for (int kb=0;kb<4;kb++)
#pragma unroll
        for (int r=0;r<4;r++){
          float p = exp2f(s[i][kb][r] + mb[kb]);
          lrun[i][r] += p;
          pw[(i*16 + g*4 + r)*72 + kb*16 + l15] = f2bf(p);
        }

    bf16x8 pa[2][2];
#pragma unroll
    for (int i=0;i<2;i++)
#pragma unroll
      for (int kk=0;kk<2;kk++)
        pa[i][kk] = *(const bf16x8*)&pw[(i*16 + l15)*72 + kk*32 + g*8];

#pragma unroll
    for (int kk=0;kk<2;kk++){
      int cs = ((kk<<2) + g) ^ (l15 & 7);
      bf16x8 vf[4];
#pragma unroll
      for (int dj=0;dj<4;dj++)
        vf[dj] = *(const bf16x8*)&VTs[buf][(dj*16 + l15)*64 + (cs<<3)];
#pragma unroll
      for (int i=0;i<2;i++)
#pragma unroll
        for (int dj=0;dj<4;dj++)
          ctxf[i][dj] = __builtin_amdgcn_mfma_f32_16x16x32_bf16(pa[i][kk], vf[dj], ctxf[i][dj], 0,0,0);
    }
  }
#undef STAGE

  float inv[2][4];
#pragma unroll
  for (int i=0;i<2;i++)
#pragma unroll
    for (int r=0;r<4;r++){
      float l = lrun[i][r];
      l += __shfl_xor(l, 1, 16);
      l += __shfl_xor(l, 2, 16);
      l += __shfl_xor(l, 4, 16);
      l += __shfl_xor(l, 8, 16);
      inv[i][r] = 1.0f / l;
    }
#pragma unroll
  for (int i=0;i<2;i++)
#pragma unroll
    for (int dj=0;dj<4;dj++)
#pragma unroll
      for (int r=0;r<4;r++)
        pw[(i*16 + g*4 + r)*64 + dj*16 + l15] = f2bf(ctxf[i][dj][r] * inv[i][r]);
#pragma unroll
  for (int t=0;t<4;t++){
    int row = lane >> 1, c = ((lane & 1)<<5) + t*8;
    const u16* pv = &pw[row*64 + c];
    u16x4 o8;
#pragma unroll
    for (int e=0;e<4;e++) o8[e] = pk_fp8(bf2f(pv[2*e]), bf2f(pv[2*e+1]));
    *(u16x4*)&CTX8[(rowbase + wq0 + row)*EE + h*DD + c] = o8;
  }
}

// ---------------------------------------------------------------------------
// K5: LayerNorm(AO + HU)*g + b + HT -> out (f32). HU/HT read as fp8.
// ---------------------------------------------------------------------------
__global__ __launch_bounds__(192,1) void ln_out_kernel(
    const u16* __restrict__ AO, const u8* __restrict__ HU8,
    const u8* __restrict__ HT8, const float* __restrict__ g,
    const float* __restrict__ bta, float* __restrict__ out)
{
  __shared__ float red[3];
  int r = blockIdx.x, tid = threadIdx.x;
  size_t base = (size_t)r*EE;
  int e0 = tid*4;
  u16x4 ao = *(const u16x4*)&AO[base+e0];
  int hu4 = *(const int*)&HU8[base+e0];
  int ht4 = *(const int*)&HT8[base+e0];
  f32x2 hulo = __builtin_amdgcn_cvt_pk_f32_fp8(hu4, false);
  f32x2 huhi = __builtin_amdgcn_cvt_pk_f32_fp8(hu4, true);
  f32x2 htlo = __builtin_amdgcn_cvt_pk_f32_fp8(ht4, false);
  f32x2 hthi = __builtin_amdgcn_cvt_pk_f32_fp8(ht4, true);
  float huv[4] = {hulo[0], hulo[1], huhi[0], huhi[1]};
  float htv[4] = {htlo[0], htlo[1], hthi[0], hthi[1]};
  float x[4];
#pragma unroll
  for (int j=0;j<4;j++) x[j] = bf2f(ao[j]) + huv[j];

  float s = x[0]+x[1]+x[2]+x[3];
#pragma unroll
  for (int o=32;o;o>>=1) s += __shfl_xor(s, o, 64);
  int w = tid>>6;
  if ((tid&63)==0) red[w] = s;
  __syncthreads();
  float mu = (red[0]+red[1]+red[2]) * (1.0f/EE);
  __syncthreads();
  float d2 = 0.f;
#pragma unroll
  for (int j=0;j<4;j++){ float d = x[j]-mu; d2 += d*d; }
#pragma unroll
  for (int o=32;o;o>>=1) d2 += __shfl_xor(d2, o, 64);
  if ((tid&63)==0) red[w] = d2;
  __syncthreads();
  float var = (red[0]+red[1]+red[2]) * (1.0f/EE);
  float rs = rsqrtf(var + 1e-12f);
  float4 gg = *(const float4*)&g[e0];
  float4 bb = *(const float4*)&bta[e0];
  float4 o4;
  o4.x = (x[0]-mu)*rs*gg.x + bb.x + htv[0];
  o4.y = (x[1]-mu)*rs*gg.y + bb.y + htv[1];
  o4.z = (x[2]-mu)*rs*gg.z + bb.z + htv[2];
  o4.w = (x[3]-mu)*rs*gg.w + bb.w + htv[3];
  *(float4*)&out[base+e0] = o4;
}

// ---------------------------------------------------------------------------
extern "C" void kernel_launch(void* const* d_in, const int* in_sizes, int n_in,
                              void* d_out, int out_size, void* d_ws, size_t ws_size,
                              hipStream_t stream)
{
  (void)in_sizes; (void)n_in; (void)out_size; (void)ws_size;
  const float* X    = (const float*)d_in[0];
  const float* mask = (const float*)d_in[1];
  const float* TE   = (const float*)d_in[2];
  const float* tp   = (const float*)d_in[3];
  const float* Wq   = (const float*)d_in[4];
  const float* bq   = (const float*)d_in[5];
  const float* Wk   = (const float*)d_in[6];
  const float* bk   = (const float*)d_in[7];
  const float* Wv   = (const float*)d_in[8];
  const float* bv   = (const float*)d_in[9];
  const float* Wo   = (const float*)d_in[10];
  const float* bo   = (const float*)d_in[11];
  const float* ln_g = (const float*)d_in[12];
  const float* ln_b = (const float*)d_in[13];

  float* out    = (float*)d_out;
  float* scores = out + BTE;

  char* p = (char*)d_ws;
  u8*  HT8  = (u8*)p;  p += BTE;                 // fp8 [8192][768]
  u8*  HU8  = (u8*)p;  p += BTE;
  u8*  CTX8 = (u8*)p;  p += BTE;
  u8*  WT8  = (u8*)p;  p += (size_t)4*EE*EE;     // fp8 4x[768][768] transposed
  u16* Qb   = (u16*)p; p += BTE*2;               // bf16
  u16* Kb   = (u16*)p; p += BTE*2;
  u16* VTb  = (u16*)p; p += BTE*2;               // bf16 [bh*64+d][512]
  u16* AOb  = (u16*)p; p += BTE*2;
  u16* ATT  = (u16*)p; p += (size_t)BT*128*2;    // bf16 [8192][128]
  u16* TEb  = (u16*)p; p += (size_t)128*EE*2;
  u16* TEt  = (u16*)p; p += (size_t)EE*128*2;
  float* MBg = (float*)p;

  prep_all_kernel<<<dim3(992), dim3(256), 0, stream>>>(
      Wq, Wk, Wv, Wo, WT8, TE, TEb, TEt, mask, MBg);

  label_scores_kernel<<<dim3(BT/16), dim3(64), 0, stream>>>(X, TEb, scores, ATT);

  // fle GEMM + fused fp8 HT/HU epilogue: M=8192, N=768, K=128
  gemm_fle_kernel<<<dim3((BT/128)*(EE/128)), dim3(256), 0, stream>>>(
      ATT, TEt, X, tp, HT8, HU8, EE, 128);

  // fused QKV projections (fp8 inputs, bf16 outputs): 64 m x 18 n
  gemm8_kernel<18,1><<<dim3(64*18), dim3(256), 0, stream>>>(
      HU8, HT8, WT8, bq, bk, bv, Qb, Kb, VTb);

  attn_mfma_kernel<<<dim3(BB*HH*4), dim3(256), 0, stream>>>(Qb, Kb, VTb, MBg, CTX8);

  // O projection (fp8 inputs): 64 x 6
  gemm8_kernel<6,0><<<dim3(64*6), dim3(256), 0, stream>>>(
      CTX8, nullptr, WT8 + 3*(size_t)EE*EE, bo, nullptr, nullptr, AOb, nullptr, nullptr);

  ln_out_kernel<<<dim3(BT), dim3(192), 0, stream>>>(AOb, HU8, HT8, ln_g, ln_b, out);
}

// Round 13
// 116.208 us; speedup vs baseline: 1.3745x; 1.0322x over previous
//
#include <hip/hip_runtime.h>

typedef unsigned char u8;
typedef unsigned short u16;
typedef u16 u16x4 __attribute__((ext_vector_type(4)));
typedef u16 u16x8 __attribute__((ext_vector_type(8)));
typedef __bf16 bf16x8 __attribute__((ext_vector_type(8)));
typedef float f32x2 __attribute__((ext_vector_type(2)));
typedef float f32x4 __attribute__((ext_vector_type(4)));
typedef long longx2 __attribute__((ext_vector_type(2)));

#define BB 16
#define TT 512
#define EE 768
#define HH 12
#define DD 64
#define LL 100
#define BT (BB*TT)             /* 8192 */
#define BTE ((size_t)BT*EE)    /* 6291456 */
#define LOG2E 1.44269504f
#define QSCALE (0.125f*LOG2E)  /* 1/sqrt(D)*log2e, folded into Q projection */
#define FIXMAX 44.0f           /* fixed softmax shift (log2 domain) */

__device__ __forceinline__ float bf2f(u16 u){
  union { float f; unsigned int i; } v; v.i = ((unsigned int)u) << 16; return v.f;
}
__device__ __forceinline__ u16 f2bf(float f){
  __bf16 h = (__bf16)f;
  union { __bf16 h; u16 u; } v; v.h = h; return v.u;
}
// fp8 e4m3 (OCP on gfx950) pack/unpack via HW cvt
__device__ __forceinline__ u16 pk_fp8(float a, float b){
  return (u16)(__builtin_amdgcn_cvt_pk_fp8_f32(a, b, 0, false) & 0xffff);
}
__device__ __forceinline__ u8 f2fp8(float a){
  return (u8)(__builtin_amdgcn_cvt_pk_fp8_f32(a, 0.f, 0, false) & 0xff);
}

// async 16B global->LDS DMA. LDS dest = wave-uniform base + lane*16.
__device__ __forceinline__ void gload16(const void* g, void* l){
  __builtin_amdgcn_global_load_lds(
      (const __attribute__((address_space(1))) void*)g,
      (__attribute__((address_space(3))) void*)l, 16, 0, 0);
}

// ---------------------------------------------------------------------------
// Merged prep: blocks 0-575 transpose+cast W[4] into FP8 [N][K];
// blocks 576-959 build TEb[128][768] / TEt[768][128] bf16; 960-991 mask bias.
// ---------------------------------------------------------------------------
__global__ __launch_bounds__(256,1) void prep_all_kernel(
    const float* __restrict__ Wq, const float* __restrict__ Wk,
    const float* __restrict__ Wv, const float* __restrict__ Wo,
    u8* __restrict__ WT8,
    const float* __restrict__ TE, u16* __restrict__ TEb, u16* __restrict__ TEt,
    const float* __restrict__ mask, float* __restrict__ MBg)
{
  __shared__ float tile[64][65];
  int bx = blockIdx.x;
  int tid = threadIdx.x;
  if (bx < 576){
    int m  = bx / 144, t = bx % 144;
    int tr = t / 12,  tc = t % 12;
    const float* W = (m==0)?Wq : (m==1)?Wk : (m==2)?Wv : Wo;
    u8* dst = WT8 + (size_t)m * EE * EE;
#pragma unroll
    for (int i=0;i<16;i++){
      int idx = tid + 256*i; int r = idx>>6, c = idx&63;
      tile[r][c] = W[(size_t)(tr*64+r)*EE + tc*64 + c];
    }
    __syncthreads();
    // dst[n][k] = W[k][n] in fp8, packed pairs along k
#pragma unroll
    for (int i=0;i<8;i++){
      int idx = tid + 256*i;          // 2048 = 64 r x 32 col-pairs
      int r = idx >> 5, cp = idx & 31;
      u16 pk = pk_fp8(tile[cp*2][r], tile[cp*2+1][r]);
      *(u16*)&dst[(size_t)(tc*64+r)*EE + tr*64 + cp*2] = pk;
    }
  } else if (bx < 960){
    int e = (bx - 576)*2 + (tid >> 7);
    int c = tid & 127;
    u16 v = 0;
    if (c < LL) v = f2bf(TE[(size_t)c*EE + e]);
    TEt[(size_t)e*128 + c] = v;
    if (e < 128){
#pragma unroll
      for (int k=c; k<EE; k+=128)
        TEb[(size_t)e*EE + k] = (e < LL) ? f2bf(TE[(size_t)e*EE + k]) : (u16)0;
    }
  } else {
    int i = (bx - 960)*256 + tid;
    MBg[i] = (1.0f - mask[i]) * (-1e9f * LOG2E) - FIXMAX;
  }
}

// ---------------------------------------------------------------------------
// K1 v2: label scores + softmax, LDS-free (unchanged).
// ---------------------------------------------------------------------------
__global__ __launch_bounds__(64) void label_scores_kernel(
    const float* __restrict__ X, const u16* __restrict__ TEb,
    float* __restrict__ scores_out, u16* __restrict__ att)
{
  int m0 = blockIdx.x * 16;
  int lane = threadIdx.x;
  int l15 = lane & 15, g = lane >> 4;

  const float* xrow = X + (size_t)(m0 + l15)*EE;
  f32x4 s[7] = {};
  for (int k0=0; k0<EE; k0+=64){
    bf16x8 af[2];
#pragma unroll
    for (int kk=0;kk<2;kk++){
      const float* src = xrow + k0 + kk*32 + g*8;
      float4 a = *(const float4*)src, b = *(const float4*)(src+4);
      bf16x8 o;
      o[0]=(__bf16)a.x; o[1]=(__bf16)a.y; o[2]=(__bf16)a.z; o[3]=(__bf16)a.w;
      o[4]=(__bf16)b.x; o[5]=(__bf16)b.y; o[6]=(__bf16)b.z; o[7]=(__bf16)b.w;
      af[kk] = o;
    }
#pragma unroll
    for (int nt=0;nt<7;nt++){
      bf16x8 b0 = *(const bf16x8*)&TEb[(size_t)(nt*16+l15)*EE + k0 + g*8];
      bf16x8 b1 = *(const bf16x8*)&TEb[(size_t)(nt*16+l15)*EE + k0 + 32 + g*8];
      s[nt] = __builtin_amdgcn_mfma_f32_16x16x32_bf16(af[0], b0, s[nt], 0,0,0);
      s[nt] = __builtin_amdgcn_mfma_f32_16x16x32_bf16(af[1], b1, s[nt], 0,0,0);
    }
  }

  int rowb = m0 + g*4;
#pragma unroll
  for (int nt=0;nt<7;nt++){
    int col = nt*16 + l15;
    if (col < LL){
#pragma unroll
      for (int r=0;r<4;r++)
        scores_out[(size_t)(rowb + r)*LL + col] = s[nt][r];
    }
  }
  if (l15 >= 4){
#pragma unroll
    for (int r=0;r<4;r++) s[6][r] = -1e30f;
  }
  float inv[4];
#pragma unroll
  for (int r=0;r<4;r++){
    float tm = s[0][r];
#pragma unroll
    for (int nt=1;nt<7;nt++) tm = fmaxf(tm, s[nt][r]);
    tm = fmaxf(tm, __shfl_xor(tm, 1, 16));
    tm = fmaxf(tm, __shfl_xor(tm, 2, 16));
    tm = fmaxf(tm, __shfl_xor(tm, 4, 16));
    tm = fmaxf(tm, __shfl_xor(tm, 8, 16));
    float ps = 0.f;
#pragma unroll
    for (int nt=0;nt<7;nt++){
      float p = exp2f((s[nt][r] - tm) * LOG2E);
      s[nt][r] = p; ps += p;
    }
    ps += __shfl_xor(ps, 1, 16);
    ps += __shfl_xor(ps, 2, 16);
    ps += __shfl_xor(ps, 4, 16);
    ps += __shfl_xor(ps, 8, 16);
    inv[r] = 1.f/ps;
  }
#pragma unroll
  for (int nt=0;nt<7;nt++){
    int col = nt*16 + l15;
#pragma unroll
    for (int r=0;r<4;r++)
      att[(size_t)(rowb + r)*128 + col] = f2bf(s[nt][r] * inv[r]);
  }
  {
    int col = 112 + l15;
#pragma unroll
    for (int r=0;r<4;r++) att[(size_t)(rowb + r)*128 + col] = 0;
  }
}

// ---------------------------------------------------------------------------
// fle GEMM (bf16 interior, K=128): HT8 = fp8(X+acc), HU8 = fp8(X+tp).
// ---------------------------------------------------------------------------
__global__ __launch_bounds__(256,1) void gemm_fle_kernel(
    const u16* __restrict__ A, const u16* __restrict__ BTw,
    const float* __restrict__ Xf, const float* __restrict__ tp,
    u8* __restrict__ HT8, u8* __restrict__ HU8, int N, int K)
{
  __shared__ u16 As[128*40];
  __shared__ u16 Bs[128*40];
  int nb = N >> 7;
  int m0 = (blockIdx.x / nb) << 7;
  int n0 = (blockIdx.x % nb) << 7;
  int tid  = threadIdx.x, lane = tid & 63, w = tid >> 6;
  int wm = (w >> 1) << 6, wn = (w & 1) << 6;
  int lr = lane & 15, lk = (lane >> 4) << 3;

  f32x4 acc[4][4] = {};

  for (int k0 = 0; k0 < K; k0 += 32){
    __syncthreads();
#pragma unroll
    for (int i=0;i<2;i++){
      int idx = tid + (i<<8);
      int row = idx >> 2, kq = (idx & 3) << 3;
      *(u16x8*)&As[row*40 + kq] = *(const u16x8*)&A  [(size_t)(m0+row)*K + k0 + kq];
      *(u16x8*)&Bs[row*40 + kq] = *(const u16x8*)&BTw[(size_t)(n0+row)*K + k0 + kq];
    }
    __syncthreads();
    bf16x8 af[4], bfr[4];
#pragma unroll
    for (int i=0;i<4;i++) af [i] = *(const bf16x8*)&As[(wm + i*16 + lr)*40 + lk];
#pragma unroll
    for (int j=0;j<4;j++) bfr[j] = *(const bf16x8*)&Bs[(wn + j*16 + lr)*40 + lk];
#pragma unroll
    for (int i=0;i<4;i++)
#pragma unroll
      for (int j=0;j<4;j++)
        acc[i][j] = __builtin_amdgcn_mfma_f32_16x16x32_bf16(af[i], bfr[j], acc[i][j], 0, 0, 0);
  }

  int rbase = (lane >> 4) << 2;
#pragma unroll
  for (int j=0;j<4;j++){
    int col = n0 + wn + j*16 + lr;
    float tpv = tp[col];
#pragma unroll
    for (int i=0;i<4;i++){
#pragma unroll
      for (int r=0;r<4;r++){
        int row = m0 + wm + i*16 + rbase + r;
        float x = Xf[(size_t)row*EE + col];
        HT8[(size_t)row*EE + col] = f2fp8(x + acc[i][j][r]);
        HU8[(size_t)row*EE + col] = f2fp8(x + tpv);
      }
    }
  }
}

// ---------------------------------------------------------------------------
// gemm8 v2: FP8 projection GEMM, k-permutation frag reads.
// Staging identical to R12 (row = 128B, gload16, source pre-swizzle rule #21:
// staged[row][c] = global[row][c ^ (row&7)]). BK=128 -> 6 k-steps.
// GEMM is K-permutation invariant (applied to A and W identically), so we
// remap: global chunk (4t+g), low 8B -> MFMA block 2t, high 8B -> block 2t+1.
// Lane's two operands for the pair = the two halves of ONE 16B chunk ->
// ds_read_b128 at cs = (4t+g)^(lr&7): byte-identical to the bf16 pattern that
// measured ZERO bank conflicts (R12's b64 split was a true 4-way: 3.54M cyc).
// Reads halve: 16 b128/wave/step vs 32 b64. MFMA/barriers unchanged.
// FUSED=1: QKV, NB=18 (Q scaled by QSCALE; V written transposed per head).
// ---------------------------------------------------------------------------
template<int NB, int FUSED>
__global__ __launch_bounds__(256,2) void gemm8_kernel(
    const u8* __restrict__ A0, const u8* __restrict__ A1,
    const u8* __restrict__ Wb,
    const float* __restrict__ b0, const float* __restrict__ b1,
    const float* __restrict__ b2,
    u16* __restrict__ C0, u16* __restrict__ C1, u16* __restrict__ C2)
{
  __shared__ __align__(16) u8 As[128*128];
  __shared__ __align__(16) u8 Bs[128*128];
  const int K = EE;   // bytes per row (1B/elt)

  int nwg = gridDim.x;
  int bid = blockIdx.x;
  int cpx = nwg >> 3;
  int swz = (bid & 7) * cpx + (bid >> 3);
  int mb = swz / NB, nb = swz % NB;
  int m0 = mb << 7;
  int n0 = (FUSED ? (nb % 6) : nb) << 7;

  int which = FUSED ? (nb / 6) : 0;
  const u8* Ap; const u8* Wp; const float* bp; u16* Cp;
  if (!FUSED){ Ap = A0; Wp = Wb; bp = b0; Cp = C0; }
  else {
    if (which == 0){ Ap = A0; Wp = Wb;                      bp = b0; Cp = C0; }
    else if (which == 1){ Ap = A1; Wp = Wb + (size_t)EE*EE; bp = b1; Cp = C1; }
    else { Ap = A1; Wp = Wb + 2*(size_t)EE*EE;              bp = b2; Cp = C2; }
  }

  int tid = threadIdx.x, lane = tid & 63, w = tid >> 6;
  int wm = (w >> 1) << 6, wn = (w & 1) << 6;
  int lr = lane & 15, g = lane >> 4;
  int lrow = lane >> 3;
  int lchunk = (lane & 7) ^ lrow;          // source pre-swizzle (rule #21)

  f32x4 acc[4][4] = {};

  for (int k0 = 0; k0 < K; k0 += 128){
    __syncthreads();
#pragma unroll
    for (int t=0;t<4;t++){
      int r0 = w*32 + t*8;
      gload16(&Ap[(size_t)(m0 + r0 + lrow)*K + k0 + (lchunk<<4)], &As[r0*128]);
      gload16(&Wp[(size_t)(n0 + r0 + lrow)*K + k0 + (lchunk<<4)], &Bs[r0*128]);
    }
    __syncthreads();
#pragma unroll
    for (int t=0;t<2;t++){
      int cs = ((t<<2) + g) ^ (lr & 7);    // 16B chunk; zero-conflict pattern
      longx2 af[4], bfr[4];
#pragma unroll
      for (int i=0;i<4;i++) af [i] = *(const longx2*)&As[(wm + i*16 + lr)*128 + (cs<<4)];
#pragma unroll
      for (int j=0;j<4;j++) bfr[j] = *(const longx2*)&Bs[(wn + j*16 + lr)*128 + (cs<<4)];
#pragma unroll
      for (int i=0;i<4;i++)
#pragma unroll
        for (int j=0;j<4;j++){
          acc[i][j] = __builtin_amdgcn_mfma_f32_16x16x32_fp8_fp8(af[i][0], bfr[j][0], acc[i][j], 0, 0, 0);
          acc[i][j] = __builtin_amdgcn_mfma_f32_16x16x32_fp8_fp8(af[i][1], bfr[j][1], acc[i][j], 0, 0, 0);
        }
    }
  }

  int rbase = (lane >> 4) << 2;
  float scq = (FUSED && which==0) ? QSCALE : 1.0f;
#pragma unroll
  for (int j=0;j<4;j++){
    int col = n0 + wn + j*16 + lr;
    float bv = bp[col];
    if (FUSED && which == 2){
      int hh = col >> 6, d = col & 63;
#pragma unroll
      for (int i=0;i<4;i++){
        int row0 = m0 + wm + i*16 + rbase;
        int bb = row0 >> 9, t0 = row0 & 511;
        u16x4 o;
#pragma unroll
        for (int r=0;r<4;r++) o[r] = f2bf(acc[i][j][r] + bv);
        *(u16x4*)&Cp[((size_t)(bb*HH + hh)*DD + d)*TT + t0] = o;
      }
    } else {
#pragma unroll
      for (int i=0;i<4;i++){
#pragma unroll
        for (int r=0;r<4;r++){
          int row = m0 + wm + i*16 + rbase + r;
          Cp[(size_t)row*EE + col] = f2bf((acc[i][j][r] + bv) * scq);
        }
      }
    }
  }
}

// ---------------------------------------------------------------------------
// K4: MFMA flash attention v4 — fixed-max softmax, bf16 (unchanged from R12).
// CTX written as fp8 for the O projection.
// ---------------------------------------------------------------------------
__global__ __launch_bounds__(256,3) void attn_mfma_kernel(
    const u16* __restrict__ Q, const u16* __restrict__ K,
    const u16* __restrict__ VT, const float* __restrict__ MBg,
    u8* __restrict__ CTX8)
{
  __shared__ u16 Ks [2][64*64];
  __shared__ u16 VTs[2][64*64];
  __shared__ u16 Pl [4][32*72];

  int bx = blockIdx.x;
  int bh = bx % (BB*HH), q0 = (bx / (BB*HH)) << 7;
  int b = bh / HH, h = bh % HH;
  int tid = threadIdx.x, lane = tid & 63, w = tid >> 6;
  int l15 = lane & 15, g = lane >> 4;
  int wq0 = q0 + w*32;
  size_t rowbase = (size_t)b*TT;
  u16* pw = &Pl[w][0];
  const u16* Kbh = K  + rowbase*EE + h*DD;
  const u16* Vbh = VT + (size_t)bh*DD*TT;
  int lrow = lane >> 3, lchunk = (lane & 7) ^ (lane >> 3);

  bf16x8 qf[2][2];
#pragma unroll
  for (int i=0;i<2;i++)
#pragma unroll
    for (int kk=0;kk<2;kk++)
      qf[i][kk] = *(const bf16x8*)&Q[(rowbase + wq0 + i*16 + l15)*EE + h*DD + kk*32 + g*8];

  f32x4 ctxf[2][4] = {};
  float lrun[2][4] = {};

#define STAGE(buf, k0)                                                          \
  { _Pragma("unroll")                                                           \
    for (int it=0; it<2; ++it){                                                 \
      int r0 = w*16 + it*8;                                                     \
      gload16(&Kbh[(size_t)((k0) + r0 + lrow)*EE + (lchunk<<3)], &Ks [buf][r0*64]); \
      gload16(&Vbh[(size_t)(r0 + lrow)*TT + (k0) + (lchunk<<3)], &VTs[buf][r0*64]); } }

  STAGE(0, 0);

  for (int kt=0; kt<8; ++kt){
    int k0 = kt << 6;
    int buf = kt & 1;
    __syncthreads();

    // mb loads FIRST (older than stage loads -> compiler waits vmcnt(4))
    float mb[4];
#pragma unroll
    for (int kb=0;kb<4;kb++) mb[kb] = MBg[rowbase + k0 + kb*16 + l15];

    if (kt < 7) STAGE(buf^1, k0+64);

    f32x4 s[2][4] = {};
#pragma unroll
    for (int kk=0;kk<2;kk++){
      int cs = ((kk<<2) + g) ^ (l15 & 7);
      bf16x8 kf[4];
#pragma unroll
      for (int kb=0;kb<4;kb++)
        kf[kb] = *(const bf16x8*)&Ks[buf][(kb*16 + l15)*64 + (cs<<3)];
#pragma unroll
      for (int i=0;i<2;i++)
#pragma unroll
        for (int kb=0;kb<4;kb++)
          s[i][kb] = __builtin_amdgcn_mfma_f32_16x16x32_bf16(qf[i][kk], kf[kb], s[i][kb], 0,0,0);
    }

    if ((k0 < wq0 + 32) && (k0 + 64 > wq0)){
#pragma unroll
      for (int i=0;i<2;i++){
        int qr = wq0 + i*16 + g*4;
#pragma unroll
        for (int kb=0;kb<4;kb++){
          int kpos = k0 + kb*16 + l15;
#pragma unroll
          for (int r=0;r<4;r++)
            if (kpos == qr + r) s[i][kb][r] -= 1e9f*LOG2E;
        }
      }
    }

#pragma unroll
    for (int i=0;i<2;i++)
#pragma unroll
      for (int kb=0;kb<4;kb++)
#pragma unroll
        for (int r=0;r<4;r++){
          float p = exp2f(s[i][kb][r] + mb[kb]);
          lrun[i][r] += p;
          pw[(i*16 + g*4 + r)*72 + kb*16 + l15] = f2bf(p);
        }

    bf16x8 pa[2][2];
#pragma unroll
    for (int i=0;i<2;i++)
#pragma unroll
      for (int kk=0;kk<2;kk++)
        pa[i][kk] = *(const bf16x8*)&pw[(i*16 + l15)*72 + kk*32 + g*8];

#pragma unroll
    for (int kk=0;kk<2;kk++){
      int cs = ((kk<<2) + g) ^ (l15 & 7);
      bf16x8 vf[4];
#pragma unroll
      for (int dj=0;dj<4;dj++)
        vf[dj] = *(const bf16x8*)&VTs[buf][(dj*16 + l15)*64 + (cs<<3)];
#pragma unroll
      for (int i=0;i<2;i++)
#pragma unroll
        for (int dj=0;dj<4;dj++)
          ctxf[i][dj] = __builtin_amdgcn_mfma_f32_16x16x32_bf16(pa[i][kk], vf[dj], ctxf[i][dj], 0,0,0);
    }
  }
#undef STAGE

  float inv[2][4];
#pragma unroll
  for (int i=0;i<2;i++)
#pragma unroll
    for (int r=0;r<4;r++){
      float l = lrun[i][r];
      l += __shfl_xor(l, 1, 16);
      l += __shfl_xor(l, 2, 16);
      l += __shfl_xor(l, 4, 16);
      l += __shfl_xor(l, 8, 16);
      inv[i][r] = 1.0f / l;
    }
#pragma unroll
  for (int i=0;i<2;i++)
#pragma unroll
    for (int dj=0;dj<4;dj++)
#pragma unroll
      for (int r=0;r<4;r++)
        pw[(i*16 + g*4 + r)*64 + dj*16 + l15] = f2bf(ctxf[i][dj][r] * inv[i][r]);
#pragma unroll
  for (int t=0;t<4;t++){
    int row = lane >> 1, c = ((lane & 1)<<5) + t*8;
    const u16* pv = &pw[row*64 + c];
    u16x4 o8;
#pragma unroll
    for (int e=0;e<4;e++) o8[e] = pk_fp8(bf2f(pv[2*e]), bf2f(pv[2*e+1]));
    *(u16x4*)&CTX8[(rowbase + wq0 + row)*EE + h*DD + c] = o8;
  }
}

// ---------------------------------------------------------------------------
// K5: LayerNorm(AO + HU)*g + b + HT -> out (f32). HU/HT read as fp8.
// ---------------------------------------------------------------------------
__global__ __launch_bounds__(192,1) void ln_out_kernel(
    const u16* __restrict__ AO, const u8* __restrict__ HU8,
    const u8* __restrict__ HT8, const float* __restrict__ g,
    const float* __restrict__ bta, float* __restrict__ out)
{
  __shared__ float red[3];
  int r = blockIdx.x, tid = threadIdx.x;
  size_t base = (size_t)r*EE;
  int e0 = tid*4;
  u16x4 ao = *(const u16x4*)&AO[base+e0];
  int hu4 = *(const int*)&HU8[base+e0];
  int ht4 = *(const int*)&HT8[base+e0];
  f32x2 hulo = __builtin_amdgcn_cvt_pk_f32_fp8(hu4, false);
  f32x2 huhi = __builtin_amdgcn_cvt_pk_f32_fp8(hu4, true);
  f32x2 htlo = __builtin_amdgcn_cvt_pk_f32_fp8(ht4, false);
  f32x2 hthi = __builtin_amdgcn_cvt_pk_f32_fp8(ht4, true);
  float huv[4] = {hulo[0], hulo[1], huhi[0], huhi[1]};
  float htv[4] = {htlo[0], htlo[1], hthi[0], hthi[1]};
  float x[4];
#pragma unroll
  for (int j=0;j<4;j++) x[j] = bf2f(ao[j]) + huv[j];

  float s = x[0]+x[1]+x[2]+x[3];
#pragma unroll
  for (int o=32;o;o>>=1) s += __shfl_xor(s, o, 64);
  int w = tid>>6;
  if ((tid&63)==0) red[w] = s;
  __syncthreads();
  float mu = (red[0]+red[1]+red[2]) * (1.0f/EE);
  __syncthreads();
  float d2 = 0.f;
#pragma unroll
  for (int j=0;j<4;j++){ float d = x[j]-mu; d2 += d*d; }
#pragma unroll
  for (int o=32;o;o>>=1) d2 += __shfl_xor(d2, o, 64);
  if ((tid&63)==0) red[w] = d2;
  __syncthreads();
  float var = (red[0]+red[1]+red[2]) * (1.0f/EE);
  float rs = rsqrtf(var + 1e-12f);
  float4 gg = *(const float4*)&g[e0];
  float4 bb = *(const float4*)&bta[e0];
  float4 o4;
  o4.x = (x[0]-mu)*rs*gg.x + bb.x + htv[0];
  o4.y = (x[1]-mu)*rs*gg.y + bb.y + htv[1];
  o4.z = (x[2]-mu)*rs*gg.z + bb.z + htv[2];
  o4.w = (x[3]-mu)*rs*gg.w + bb.w + htv[3];
  *(float4*)&out[base+e0] = o4;
}

// ---------------------------------------------------------------------------
extern "C" void kernel_launch(void* const* d_in, const int* in_sizes, int n_in,
                              void* d_out, int out_size, void* d_ws, size_t ws_size,
                              hipStream_t stream)
{
  (void)in_sizes; (void)n_in; (void)out_size; (void)ws_size;
  const float* X    = (const float*)d_in[0];
  const float* mask = (const float*)d_in[1];
  const float* TE   = (const float*)d_in[2];
  const float* tp   = (const float*)d_in[3];
  const float* Wq   = (const float*)d_in[4];
  const float* bq   = (const float*)d_in[5];
  const float* Wk   = (const float*)d_in[6];
  const float* bk   = (const float*)d_in[7];
  const float* Wv   = (const float*)d_in[8];
  const float* bv   = (const float*)d_in[9];
  const float* Wo   = (const float*)d_in[10];
  const float* bo   = (const float*)d_in[11];
  const float* ln_g = (const float*)d_in[12];
  const float* ln_b = (const float*)d_in[13];

  float* out    = (float*)d_out;
  float* scores = out + BTE;

  char* p = (char*)d_ws;
  u8*  HT8  = (u8*)p;  p += BTE;                 // fp8 [8192][768]
  u8*  HU8  = (u8*)p;  p += BTE;
  u8*  CTX8 = (u8*)p;  p += BTE;
  u8*  WT8  = (u8*)p;  p += (size_t)4*EE*EE;     // fp8 4x[768][768] transposed
  u16* Qb   = (u16*)p; p += BTE*2;               // bf16
  u16* Kb   = (u16*)p; p += BTE*2;
  u16* VTb  = (u16*)p; p += BTE*2;               // bf16 [bh*64+d][512]
  u16* AOb  = (u16*)p; p += BTE*2;
  u16* ATT  = (u16*)p; p += (size_t)BT*128*2;    // bf16 [8192][128]
  u16* TEb  = (u16*)p; p += (size_t)128*EE*2;
  u16* TEt  = (u16*)p; p += (size_t)EE*128*2;
  float* MBg = (float*)p;

  prep_all_kernel<<<dim3(992), dim3(256), 0, stream>>>(
      Wq, Wk, Wv, Wo, WT8, TE, TEb, TEt, mask, MBg);

  label_scores_kernel<<<dim3(BT/16), dim3(64), 0, stream>>>(X, TEb, scores, ATT);

  // fle GEMM + fused fp8 HT/HU epilogue: M=8192, N=768, K=128
  gemm_fle_kernel<<<dim3((BT/128)*(EE/128)), dim3(256), 0, stream>>>(
      ATT, TEt, X, tp, HT8, HU8, EE, 128);

  // fused QKV projections (fp8 inputs, bf16 outputs): 64 m x 18 n
  gemm8_kernel<18,1><<<dim3(64*18), dim3(256), 0, stream>>>(
      HU8, HT8, WT8, bq, bk, bv, Qb, Kb, VTb);

  attn_mfma_kernel<<<dim3(BB*HH*4), dim3(256), 0, stream>>>(Qb, Kb, VTb, MBg, CTX8);

  // O projection (fp8 inputs): 64 x 6
  gemm8_kernel<6,0><<<dim3(64*6), dim3(256), 0, stream>>>(
      CTX8, nullptr, WT8 + 3*(size_t)EE*EE, bo, nullptr, nullptr, AOb, nullptr, nullptr);

  ln_out_kernel<<<dim3(BT), dim3(192), 0, stream>>>(AOb, HU8, HT8, ln_g, ln_b, out);
}